// Round 19
// baseline (134.158 us; speedup 1.0000x reference)
//
#include <hip/hip_runtime.h>
#include <hip/hip_bf16.h>

#define BATCH 128
#define AST 88  // conv34 padded-A LDS row stride in ushorts (176B, 16B-aligned)

typedef __attribute__((ext_vector_type(8))) short bf16x8;
typedef __attribute__((ext_vector_type(16))) float f32x16;

// ---------------------------------------------------------------------------
// Spline activation: act[0] = silu(x), act[1..8] = cubic B-spline bases
// ---------------------------------------------------------------------------
__device__ __forceinline__ void spline_acts(float xv, float act[9]) {
    act[0] = xv * (1.0f / (1.0f + __expf(-xv)));  // silu
    float g[12];
#pragma unroll
    for (int i = 0; i < 12; ++i) g[i] = (float)(i - 3) * 0.4f - 1.0f;
    float bb[11];
#pragma unroll
    for (int c = 0; c < 11; ++c) bb[c] = (xv >= g[c] && xv < g[c + 1]) ? 1.0f : 0.0f;
#pragma unroll
    for (int k = 1; k <= 3; ++k) {
#pragma unroll
        for (int c = 0; c + k < 11; ++c) {
            float left  = (xv - g[c]) * (1.0f / (g[c + k] - g[c])) * bb[c];
            float right = (g[c + k + 1] - xv) * (1.0f / (g[c + k + 1] - g[c + 1])) * bb[c + 1];
            bb[c] = left + right;
        }
    }
#pragma unroll
    for (int c = 0; c < 8; ++c) act[c + 1] = bb[c];
}

__device__ __constant__ float ZPAD[9] = {0.0f, 0.0f, 0.0f, 0.02083333333f,
                                         0.47916666667f, 0.47916666667f,
                                         0.02083333333f, 0.0f, 0.0f};

// bf16 hi/lo split via HW RNE converts
__device__ __forceinline__ void bf16split(float x, ushort& h, ushort& l) {
    __hip_bfloat16 bh = __float2bfloat16(x);
    float hf = __bfloat162float(bh);
    __hip_bfloat16 bl = __float2bfloat16(x - hf);
    h = *(ushort*)&bh;
    l = *(ushort*)&bl;
}

// packed conv weight value: f = cin*9 + tap, j = spline idx
__device__ __forceinline__ float wval(const float* bw, const float* sw, const float* sc,
                                      int F, int f, int j, int o) {
    if (j == 0) return bw[o * F + f];
    return sw[(o * F + f) * 8 + (j - 1)] * sc[o * F + f];
}

// ---------------------------------------------------------------------------
// prep: pack MFMA B-fragments (bf16 hi/lo) for all 4 conv layers + zp pattern.
// ---------------------------------------------------------------------------
__global__ __launch_bounds__(256) void prep_kernel(
    const float* __restrict__ bw1, const float* __restrict__ sw1, const float* __restrict__ sc1,
    const float* __restrict__ bw2, const float* __restrict__ sw2, const float* __restrict__ sc2,
    const float* __restrict__ bw3, const float* __restrict__ sw3, const float* __restrict__ sc3,
    const float* __restrict__ bw4, const float* __restrict__ sw4, const float* __restrict__ sc4,
    ushort* __restrict__ k1h, ushort* __restrict__ k1l,
    ushort* __restrict__ k2h, ushort* __restrict__ k2l,
    ushort* __restrict__ k3h, ushort* __restrict__ k3l,
    ushort* __restrict__ k4h, ushort* __restrict__ k4l,
    ushort* __restrict__ zph, ushort* __restrict__ zpl) {
    int i = blockIdx.x * 256 + threadIdx.x;
    if (i < 1152) {                            // conv1
        int l = i & 63, s = (i >> 6) & 1, t = i / 128;
#pragma unroll
        for (int e = 0; e < 8; ++e) {
            int k = s * 16 + ((l >> 5) * 8) + e, o = l & 31;
            float w = 0.f;
            if (k < 27 && o < 4) w = wval(bw1, sw1, sc1, 27, (k / 9) * 9 + t, k % 9, o);
            ushort h, lo; bf16split(w, h, lo);
            k1h[i * 8 + e] = h; k1l[i * 8 + e] = lo;
        }
    } else if (i < 2880) {                     // conv2
        int q = i - 1152;
        int l = q & 63, s = (q >> 6) % 3, t = q / 192;
#pragma unroll
        for (int e = 0; e < 8; ++e) {
            int k = s * 16 + ((l >> 5) * 8) + e, o = l & 31;
            float w = 0.f;
            if (k < 36 && o < 8) w = wval(bw2, sw2, sc2, 36, (k / 9) * 9 + t, k % 9, o);
            ushort h, lo; bf16split(w, h, lo);
            k2h[q * 8 + e] = h; k2l[q * 8 + e] = lo;
        }
    } else if (i < 5760) {                     // conv3
        int q = i - 2880;
        int l = q & 63, s = (q >> 6) % 5, t = q / 320;
#pragma unroll
        for (int e = 0; e < 8; ++e) {
            int k = s * 16 + ((l >> 5) * 8) + e, o = l & 31;
            float w = 0.f;
            if (k < 72 && o < 16) w = wval(bw3, sw3, sc3, 72, (k / 9) * 9 + t, k % 9, o);
            ushort h, lo; bf16split(w, h, lo);
            k3h[q * 8 + e] = h; k3l[q * 8 + e] = lo;
        }
    } else if (i < 11520) {                    // conv4
        int q = i - 5760;
        int l = q & 63, s = (q >> 6) % 5, t = (q / 320) % 9, p = q / 2880;
#pragma unroll
        for (int e = 0; e < 8; ++e) {
            int k = s * 16 + ((l >> 5) * 8) + e, o = l & 31;
            float w = 0.f;
            if (k < 72) w = wval(bw4, sw4, sc4, 144, (p * 8 + k / 9) * 9 + t, k % 9, o);
            ushort h, lo; bf16split(w, h, lo);
            k4h[q * 8 + e] = h; k4l[q * 8 + e] = lo;
        }
    } else if (i < 11600) {
        int c = i - 11520;
        ushort h, lo; bf16split(ZPAD[c % 9], h, lo);
        zph[c] = h; zpl[c] = lo;
    }
}

// ---------------------------------------------------------------------------
// conv1_fused v4 (verified): 4-row strips, ASTR=40, linear addressing.
// ---------------------------------------------------------------------------
__global__ __launch_bounds__(256) void conv1_fused(
    const float* __restrict__ x,
    const ushort* __restrict__ Bgh, const ushort* __restrict__ Bgl,
    ushort* __restrict__ Oh, ushort* __restrict__ Ol) {
    constexpr int ASTR = 40, KSTEPS = 2, NCO = 4;
    __shared__ ushort AH[204 * ASTR];
    __shared__ ushort AL[204 * ASTR];
    const int tid = threadIdx.x;
    const int b = blockIdx.x >> 3, strip = blockIdx.x & 7;
    const int r0 = strip * 4;
    const int lane = tid & 63, wv = tid >> 6;

    for (int px = tid; px < 204; px += 256) {
        int lr = px / 34, pc = px - lr * 34;
        int grow = r0 - 1 + lr, gc = pc - 1;
        bool inb = ((unsigned)grow < 32u) && ((unsigned)gc < 32u);
        unsigned rh[16], rl[16];
#pragma unroll
        for (int w = 0; w < 16; ++w) { rh[w] = 0u; rl[w] = 0u; }
        if (inb) {
            const float* xb = x + (size_t)b * 3072 + grow * 32 + gc;
#pragma unroll
            for (int cin = 0; cin < 3; ++cin) {
                float a9[9];
                spline_acts(xb[cin * 1024], a9);
#pragma unroll
                for (int j = 0; j < 9; ++j) {
                    ushort h, l2; bf16split(a9[j], h, l2);
                    int c = cin * 9 + j;
                    if (c & 1) { rh[c >> 1] |= (unsigned)h << 16; rl[c >> 1] |= (unsigned)l2 << 16; }
                    else       { rh[c >> 1] |= h;                  rl[c >> 1] |= l2; }
                }
            }
        } else {
#pragma unroll
            for (int c = 0; c < 27; ++c) {
                ushort h, l2; bf16split(ZPAD[c % 9], h, l2);
                if (c & 1) { rh[c >> 1] |= (unsigned)h << 16; rl[c >> 1] |= (unsigned)l2 << 16; }
                else       { rh[c >> 1] |= h;                  rl[c >> 1] |= l2; }
            }
        }
        unsigned* dh = (unsigned*)&AH[px * ASTR];
        unsigned* dl = (unsigned*)&AL[px * ASTR];
#pragma unroll
        for (int w = 0; w < 16; ++w) { dh[w] = rh[w]; dl[w] = rl[w]; }
    }
    __syncthreads();

    f32x16 acc;
#pragma unroll
    for (int i = 0; i < 16; ++i) acc[i] = 0.f;

    const int p0 = wv * 32 + (lane & 31);
    const int sp0 = ((p0 >> 5) + 1) * 34 + (p0 & 31) + 1;
    const int koff = (lane >> 5) * 8;

#pragma unroll 1
    for (int t = 0; t < 9; ++t) {
        const int dA = ((t / 3) - 1) * 34 + (t % 3) - 1;
#pragma unroll
        for (int s = 0; s < KSTEPS; ++s) {
            bf16x8 ah = *(const bf16x8*)(&AH[(sp0 + dA) * ASTR + s * 16 + koff]);
            bf16x8 al = *(const bf16x8*)(&AL[(sp0 + dA) * ASTR + s * 16 + koff]);
            bf16x8 bh = *(const bf16x8*)(Bgh + (size_t)((t * KSTEPS + s) * 64 + lane) * 8);
            bf16x8 bl = *(const bf16x8*)(Bgl + (size_t)((t * KSTEPS + s) * 64 + lane) * 8);
            acc = __builtin_amdgcn_mfma_f32_32x32x16_bf16(ah, bh, acc, 0, 0, 0);
            acc = __builtin_amdgcn_mfma_f32_32x32x16_bf16(ah, bl, acc, 0, 0, 0);
            acc = __builtin_amdgcn_mfma_f32_32x32x16_bf16(al, bh, acc, 0, 0, 0);
        }
    }
    __syncthreads();

    float* fl = (float*)AH;
    {
        int ccol = lane & 31;
        if (ccol < NCO) {
#pragma unroll
            for (int r = 0; r < 16; ++r) {
                int row = (r & 3) + 8 * (r >> 2) + 4 * (lane >> 5);
                fl[ccol * 129 + wv * 32 + row] = acc[r];
            }
        }
    }
    __syncthreads();

    unsigned* ubh = (unsigned*)AL;
    unsigned* ubl = (unsigned*)AH + 1032;
    {
        int px = tid >> 1, cop = tid & 1;
        unsigned rwh[9], rwl[9];
#pragma unroll
        for (int w = 0; w < 9; ++w) { rwh[w] = 0u; rwl[w] = 0u; }
#pragma unroll
        for (int e = 0; e < 2; ++e) {
            int co = cop * 2 + e;
            float a9[9];
            spline_acts(fl[co * 129 + px], a9);
#pragma unroll
            for (int j = 0; j < 9; ++j) {
                ushort h, l2; bf16split(a9[j], h, l2);
                int c = e * 9 + j;
                if (c & 1) { rwh[c >> 1] |= (unsigned)h << 16; rwl[c >> 1] |= (unsigned)l2 << 16; }
                else       { rwh[c >> 1] |= h;                  rwl[c >> 1] |= l2; }
            }
        }
#pragma unroll
        for (int w = 0; w < 9; ++w) {
            ubh[px * 18 + cop * 9 + w] = rwh[w];
            ubl[px * 18 + cop * 9 + w] = rwl[w];
        }
    }
    __syncthreads();
    size_t basew = ((size_t)b * 1024 + strip * 128) * 18;
    unsigned* goh = (unsigned*)Oh + basew;
    unsigned* gol = (unsigned*)Ol + basew;
#pragma unroll
    for (int e = 0; e < 9; ++e) {
        int q = e * 256 + tid;
        goh[q] = ubh[q];
        gol[q] = ubl[q];
    }
}

// ---------------------------------------------------------------------------
// conv2_strip4: 4-row strips (grid 1024), ASTR=56, LDS 45.7KB -> 3 blocks/CU.
// A2 (B,1024,36) -> MFMA -> 2x2 pool + spline -> A3 (B,256,80).
// ---------------------------------------------------------------------------
__global__ __launch_bounds__(256) void conv2_strip4(
    const ushort* __restrict__ Agh, const ushort* __restrict__ Agl,
    const ushort* __restrict__ Bgh, const ushort* __restrict__ Bgl,
    const ushort* __restrict__ zph, const ushort* __restrict__ zpl,
    ushort* __restrict__ Oh, ushort* __restrict__ Ol) {
    constexpr int ASTR = 56, KSTEPS = 3, NCO = 8, CHG = 9, CHL = 12;
    __shared__ ushort AH[204 * ASTR];  // 22848 B
    __shared__ ushort AL[204 * ASTR];
    const int tid = threadIdx.x;
    const int b = blockIdx.x >> 3, strip = blockIdx.x & 7;
    const int r0 = strip * 4;
    const int lane = tid & 63, wv = tid >> 6;

    // stage 204 slots x 12 uint2-chunks (real 9; ch>=9 zero)
    {
        const ushort* ash = Agh + (size_t)b * 1024 * 36;
        const ushort* asl = Agl + (size_t)b * 1024 * 36;
        for (int idx = tid; idx < 204 * CHL; idx += 256) {
            int pxl = idx / CHL, ch = idx - pxl * CHL;
            int lr = pxl / 34, pc = pxl - lr * 34;
            int grow = r0 - 1 + lr, gc = pc - 1;
            bool inb = ((unsigned)grow < 32u) && ((unsigned)gc < 32u);
            uint2 vh, vl;
            if (ch >= CHG) { vh = make_uint2(0u, 0u); vl = make_uint2(0u, 0u); }
            else if (inb) {
                vh = *(const uint2*)(ash + (size_t)(grow * 32 + gc) * 36 + ch * 4);
                vl = *(const uint2*)(asl + (size_t)(grow * 32 + gc) * 36 + ch * 4);
            } else {
                vh = *(const uint2*)(zph + ch * 4);
                vl = *(const uint2*)(zpl + ch * 4);
            }
            *(uint2*)(&AH[pxl * ASTR + ch * 4]) = vh;
            *(uint2*)(&AL[pxl * ASTR + ch * 4]) = vl;
        }
    }
    __syncthreads();

    f32x16 acc;
#pragma unroll
    for (int i = 0; i < 16; ++i) acc[i] = 0.f;

    const int p0 = wv * 32 + (lane & 31);                 // local px 0..127
    const int sp0 = ((p0 >> 5) + 1) * 34 + (p0 & 31) + 1; // staged slot
    const int koff = (lane >> 5) * 8;

#pragma unroll 1
    for (int t = 0; t < 9; ++t) {
        const int dA = ((t / 3) - 1) * 34 + (t % 3) - 1;
#pragma unroll
        for (int s = 0; s < KSTEPS; ++s) {
            bf16x8 ah = *(const bf16x8*)(&AH[(sp0 + dA) * ASTR + s * 16 + koff]);
            bf16x8 al = *(const bf16x8*)(&AL[(sp0 + dA) * ASTR + s * 16 + koff]);
            bf16x8 bh = *(const bf16x8*)(Bgh + (size_t)((t * KSTEPS + s) * 64 + lane) * 8);
            bf16x8 bl = *(const bf16x8*)(Bgl + (size_t)((t * KSTEPS + s) * 64 + lane) * 8);
            acc = __builtin_amdgcn_mfma_f32_32x32x16_bf16(ah, bh, acc, 0, 0, 0);
            acc = __builtin_amdgcn_mfma_f32_32x32x16_bf16(ah, bl, acc, 0, 0, 0);
            acc = __builtin_amdgcn_mfma_f32_32x32x16_bf16(al, bh, acc, 0, 0, 0);
        }
    }
    __syncthreads();

    // transpose acc -> fl [NCO][129] at start of AH (2064 words < 5712)
    float* fl = (float*)AH;
    {
        int ccol = lane & 31;
        if (ccol < NCO) {
#pragma unroll
            for (int r = 0; r < 16; ++r) {
                int row = (r & 3) + 8 * (r >> 2) + 4 * (lane >> 5);
                fl[ccol * 129 + wv * 32 + row] = acc[r];
            }
        }
    }
    __syncthreads();

    // 2x2 pool + spline -> bounce (32 px x 80 cols); thread = (co, pooled px)
    unsigned* ubh = (unsigned*)AL;          // 1280 words
    unsigned* ubl = (unsigned*)AL + 1280;   // 1280 words (AL = 5712 words)
    {
        int co = tid >> 5, pl = tid & 31;
        int prl = pl >> 4, pw = pl & 15;
        int base_m = (2 * prl) * 32 + 2 * pw;
        const float* fb = fl + co * 129 + base_m;
        float m = fmaxf(fmaxf(fb[0], fb[1]), fmaxf(fb[32], fb[33]));
        float a9[9];
        spline_acts(m, a9);
        ushort* bh2 = (ushort*)ubh + pl * 80 + co * 9;
        ushort* bl2 = (ushort*)ubl + pl * 80 + co * 9;
#pragma unroll
        for (int j = 0; j < 9; ++j) {
            ushort h, l2; bf16split(a9[j], h, l2);
            bh2[j] = h;
            bl2[j] = l2;
        }
        if (co == 7) {
            ushort* ph2 = (ushort*)ubh + pl * 80 + 72;
            ushort* pl2 = (ushort*)ubl + pl * 80 + 72;
#pragma unroll
            for (int w = 0; w < 8; ++w) { ph2[w] = 0; pl2[w] = 0; }
        }
    }
    __syncthreads();
    // copy out 32 px x 80 ushorts = 320 uint4 per buffer
    size_t base = ((size_t)b * 256 + strip * 32) * 80;
    const ushort* sbh = (const ushort*)ubh;
    const ushort* sbl = (const ushort*)ubl;
#pragma unroll
    for (int e = 0; e < 2; ++e) {
        int q = e * 256 + tid;
        if (q < 320) {
            *(uint4*)(Oh + base + q * 8) = *(const uint4*)(sbh + q * 8);
            *(uint4*)(Ol + base + q * 8) = *(const uint4*)(sbl + q * 8);
        }
    }
}

// ---------------------------------------------------------------------------
// conv34_part: split-K MFMA partial, z = dh-group (3); cin-phases looped.
// ---------------------------------------------------------------------------
template <int NPH, int NCO>
__global__ __launch_bounds__(256) void conv34_part(
    const ushort* __restrict__ Agh, const ushort* __restrict__ Agl,
    const ushort* __restrict__ Bgh, const ushort* __restrict__ Bgl,
    const ushort* __restrict__ zph, const ushort* __restrict__ zpl,
    float* __restrict__ P) {
    __shared__ ushort AH[144 * AST];
    __shared__ ushort AL[144 * AST];
    const int tid = threadIdx.x;
    const int b = blockIdx.x, half = blockIdx.y, g = blockIdx.z;
    const int r0 = half * 8;
    const int lane = tid & 63, wv = tid >> 6;

    f32x16 acc;
#pragma unroll
    for (int i = 0; i < 16; ++i) acc[i] = 0.f;

    const int m = wv * 32 + (lane & 31);
    const int sbase = (m >> 4) * 18 + (m & 15);
    const int koff = (lane >> 5) * 8;

#pragma unroll 1
    for (int p = 0; p < NPH; ++p) {
        if (p) __syncthreads();
        const ushort* ash = Agh + ((size_t)b * NPH + p) * 256 * 80;
        const ushort* asl = Agl + ((size_t)b * NPH + p) * 256 * 80;
#pragma unroll
        for (int e = 0; e < 6; ++e) {
            int idx = e * 256 + tid;
            if (idx < 1440) {
                int px = idx / 10, ch = idx - px * 10;
                int pr = px / 18, pc = px - pr * 18;
                int r = r0 - 1 + g + pr, c = pc - 1;
                bool inb = ((unsigned)r < 16u) && ((unsigned)c < 16u);
                uint4 vh, vl;
                if (inb) {
                    vh = *(const uint4*)(ash + (size_t)(r * 16 + c) * 80 + ch * 8);
                    vl = *(const uint4*)(asl + (size_t)(r * 16 + c) * 80 + ch * 8);
                } else {
                    vh = *(const uint4*)(zph + ch * 8);
                    vl = *(const uint4*)(zpl + ch * 8);
                }
                *(uint4*)(&AH[px * AST + ch * 8]) = vh;
                *(uint4*)(&AL[px * AST + ch * 8]) = vl;
            }
        }
        __syncthreads();

        const ushort* bsh = Bgh + (size_t)p * 2880 * 8;
        const ushort* bsl = Bgl + (size_t)p * 2880 * 8;
#pragma unroll
        for (int dw = 0; dw < 3; ++dw) {
            const int t = g * 3 + dw;
#pragma unroll
            for (int s = 0; s < 5; ++s) {
                bf16x8 ah = *(const bf16x8*)(&AH[(sbase + dw) * AST + s * 16 + koff]);
                bf16x8 al = *(const bf16x8*)(&AL[(sbase + dw) * AST + s * 16 + koff]);
                bf16x8 bh = *(const bf16x8*)(bsh + (size_t)((t * 5 + s) * 64 + lane) * 8);
                bf16x8 bl = *(const bf16x8*)(bsl + (size_t)((t * 5 + s) * 64 + lane) * 8);
                acc = __builtin_amdgcn_mfma_f32_32x32x16_bf16(ah, bh, acc, 0, 0, 0);
                acc = __builtin_amdgcn_mfma_f32_32x32x16_bf16(ah, bl, acc, 0, 0, 0);
                acc = __builtin_amdgcn_mfma_f32_32x32x16_bf16(al, bh, acc, 0, 0, 0);
            }
        }
    }

    int co = lane & 31;
    if (co < NCO) {
        float* pb = P + ((size_t)(g * 256 + b * 2 + half) * 128) * NCO;
#pragma unroll
        for (int r = 0; r < 16; ++r) {
            int px = wv * 32 + (r & 3) + 8 * (r >> 2) + 4 * (lane >> 5);
            pb[px * NCO + co] = acc[r];
        }
    }
}

// ---------------------------------------------------------------------------
// conv3_reduce v3: block = (b, px-quarter), all 16 couts, 64 px.
// ---------------------------------------------------------------------------
__global__ __launch_bounds__(256) void conv3_reduce(const float* __restrict__ P3,
                                                    ushort* __restrict__ A4h,
                                                    ushort* __restrict__ A4l) {
    __shared__ ushort SBH[2][64 * 80];
    __shared__ ushort SBL[2][64 * 80];
    int b = blockIdx.x, pxq = blockIdx.y;
    int t = threadIdx.x;
    int co = t & 15, pxg = t >> 4;
#pragma unroll
    for (int q = 0; q < 4; ++q) {
        int lpx64 = pxg * 4 + q;
        int px = pxq * 64 + lpx64;
        int bh = b * 2 + (px >> 7), lpx = px & 127;
        float s = 0.f;
#pragma unroll
        for (int zz = 0; zz < 3; ++zz)
            s += P3[((size_t)(zz * 256 + bh) * 128 + lpx) * 16 + co];
        float a9[9];
        spline_acts(s, a9);
        int ph = co >> 3, c8 = co & 7;
#pragma unroll
        for (int j = 0; j < 9; ++j) {
            ushort h, l2; bf16split(a9[j], h, l2);
            SBH[ph][lpx64 * 80 + c8 * 9 + j] = h;
            SBL[ph][lpx64 * 80 + c8 * 9 + j] = l2;
        }
        if (c8 == 7) {
#pragma unroll
            for (int w = 0; w < 8; ++w) {
                SBH[ph][lpx64 * 80 + 72 + w] = 0;
                SBL[ph][lpx64 * 80 + 72 + w] = 0;
            }
        }
    }
    __syncthreads();
#pragma unroll
    for (int ph = 0; ph < 2; ++ph) {
        size_t base = ((size_t)(b * 2 + ph) * 256 + pxq * 64) * 80;
#pragma unroll
        for (int e = 0; e < 3; ++e) {
            int q = e * 256 + t;
            if (q < 640) {
                *(uint4*)(A4h + base + q * 8) = *(const uint4*)(&SBH[ph][q * 8]);
                *(uint4*)(A4l + base + q * 8) = *(const uint4*)(&SBL[ph][q * 8]);
            }
        }
    }
}

// ---------------------------------------------------------------------------
// conv4_reduce_pool v2: block = (b, half); sum 3 partials + 2x2 pool.
// ---------------------------------------------------------------------------
__global__ __launch_bounds__(256) void conv4_reduce_pool(const float* __restrict__ P4,
                                                         float* __restrict__ pooled) {
    __shared__ float SM[32 * 33];
    int b = blockIdx.x, half = blockIdx.y;
    int t = threadIdx.x;
    int co = t & 31, pg = t >> 5;
    int bh = b * 2 + half;
#pragma unroll
    for (int q = 0; q < 4; ++q) {
        int pp = pg * 4 + q;
        int lr = pp >> 3, pc = pp & 7;
        int px00 = (2 * lr) * 16 + 2 * pc;
        float s00 = 0.f, s01 = 0.f, s10 = 0.f, s11 = 0.f;
#pragma unroll
        for (int zz = 0; zz < 3; ++zz) {
            const float* pb = P4 + ((size_t)(zz * 256 + bh) * 128) * 32 + co;
            s00 += pb[(size_t)px00 * 32];
            s01 += pb[(size_t)(px00 + 1) * 32];
            s10 += pb[(size_t)(px00 + 16) * 32];
            s11 += pb[(size_t)(px00 + 17) * 32];
        }
        SM[co * 33 + pp] = fmaxf(fmaxf(s00, s01), fmaxf(s10, s11));
    }
    __syncthreads();
#pragma unroll
    for (int e = 0; e < 4; ++e) {
        int idx = e * 256 + t;
        int co2 = idx >> 5, pp2 = idx & 31;
        int lr2 = pp2 >> 3, pc2 = pp2 & 7;
        pooled[(size_t)b * 2048 + co2 * 64 + (half * 4 + lr2) * 8 + pc2] = SM[co2 * 33 + pp2];
    }
}

// ---------------------------------------------------------------------------
// fc_big: 64x64 tile, 4x4/thread, K_TILE=32, split-K; float4 global staging.
// ---------------------------------------------------------------------------
template <int SPLIT>
__global__ __launch_bounds__(256) void fc_big(const float* __restrict__ A,
                                              const float* __restrict__ Wt,
                                              float* __restrict__ part,
                                              int M, int N, int K) {
    __shared__ float As[32][68];
    __shared__ float Ws[32][68];
    const int tid = threadIdx.x;
    const int tx = tid & 15, ty = tid >> 4;
    const int bm = blockIdx.y * 64, bn = blockIdx.x * 64;
    const int kc = K / SPLIT;
    const int kbeg = blockIdx.z * kc;
    float acc[4][4] = {};
    for (int k0 = kbeg; k0 < kbeg + kc; k0 += 32) {
#pragma unroll
        for (int e = 0; e < 2; ++e) {
            int q = e * 256 + tid;
            int r = q >> 3, k4 = (q & 7) * 4;
            float4 av = *(const float4*)&A[(size_t)(bm + r) * K + k0 + k4];
            float4 wv = *(const float4*)&Wt[(size_t)(bn + r) * K + k0 + k4];
            As[k4 + 0][r] = av.x; As[k4 + 1][r] = av.y;
            As[k4 + 2][r] = av.z; As[k4 + 3][r] = av.w;
            Ws[k4 + 0][r] = wv.x; Ws[k4 + 1][r] = wv.y;
            Ws[k4 + 2][r] = wv.z; Ws[k4 + 3][r] = wv.w;
        }
        __syncthreads();
#pragma unroll
        for (int kk = 0; kk < 32; ++kk) {
            float4 av = *(const float4*)(&As[kk][ty * 4]);
            float4 wv = *(const float4*)(&Ws[kk][tx * 4]);
            acc[0][0] = fmaf(av.x, wv.x, acc[0][0]);
            acc[0][1] = fmaf(av.x, wv.y, acc[0][1]);
            acc[0][2] = fmaf(av.x, wv.z, acc[0][2]);
            acc[0][3] = fmaf(av.x, wv.w, acc[0][3]);
            acc[1][0] = fmaf(av.y, wv.x, acc[1][0]);
            acc[1][1] = fmaf(av.y, wv.y, acc[1][1]);
            acc[1][2] = fmaf(av.y, wv.z, acc[1][2]);
            acc[1][3] = fmaf(av.y, wv.w, acc[1][3]);
            acc[2][0] = fmaf(av.z, wv.x, acc[2][0]);
            acc[2][1] = fmaf(av.z, wv.y, acc[2][1]);
            acc[2][2] = fmaf(av.z, wv.z, acc[2][2]);
            acc[2][3] = fmaf(av.z, wv.w, acc[2][3]);
            acc[3][0] = fmaf(av.w, wv.x, acc[3][0]);
            acc[3][1] = fmaf(av.w, wv.y, acc[3][1]);
            acc[3][2] = fmaf(av.w, wv.z, acc[3][2]);
            acc[3][3] = fmaf(av.w, wv.w, acc[3][3]);
        }
        __syncthreads();
    }
    float* p = part + (size_t)blockIdx.z * M * N;
#pragma unroll
    for (int i = 0; i < 4; ++i) {
        float4 v = make_float4(acc[i][0], acc[i][1], acc[i][2], acc[i][3]);
        *(float4*)&p[(size_t)(bm + ty * 4 + i) * N + (bn + tx * 4)] = v;
    }
}

template <int SPLIT>
__global__ void fc_reduce(const float* __restrict__ part, const float* __restrict__ bias,
                          float* __restrict__ C, int MN, int N, int relu) {
    int i = blockIdx.x * 256 + threadIdx.x;
    if (i >= MN) return;
    float s = bias[i % N];
#pragma unroll
    for (int z = 0; z < SPLIT; ++z) s += part[(size_t)z * MN + i];
    C[i] = relu ? fmaxf(s, 0.f) : s;
}

__global__ __launch_bounds__(256) void fc3_kernel(const float* __restrict__ A,
                                                  const float* __restrict__ Wt,
                                                  const float* __restrict__ bias,
                                                  float* __restrict__ C) {
    int gid = blockIdx.x * 256 + threadIdx.x;
    int wid = gid >> 6;
    int lane = gid & 63;
    int m = wid / 10, n = wid - m * 10;
    const float4* a = (const float4*)(A + (size_t)m * 1024);
    const float4* w = (const float4*)(Wt + (size_t)n * 1024);
    float s = 0.f;
#pragma unroll
    for (int it = 0; it < 4; ++it) {
        float4 av = a[it * 64 + lane];
        float4 wv = w[it * 64 + lane];
        s += av.x * wv.x + av.y * wv.y + av.z * wv.z + av.w * wv.w;
    }
#pragma unroll
    for (int off = 32; off; off >>= 1) s += __shfl_xor(s, off);
    if (lane == 0) C[wid] = s + bias[n];
}

// ---------------------------------------------------------------------------
extern "C" void kernel_launch(void* const* d_in, const int* in_sizes, int n_in,
                              void* d_out, int out_size, void* d_ws, size_t ws_size,
                              hipStream_t stream) {
    const float* x   = (const float*)d_in[0];
    const float* bw1 = (const float*)d_in[1];
    const float* sw1 = (const float*)d_in[2];
    const float* sc1 = (const float*)d_in[3];
    const float* bw2 = (const float*)d_in[4];
    const float* sw2 = (const float*)d_in[5];
    const float* sc2 = (const float*)d_in[6];
    const float* bw3 = (const float*)d_in[7];
    const float* sw3 = (const float*)d_in[8];
    const float* sc3 = (const float*)d_in[9];
    const float* bw4 = (const float*)d_in[10];
    const float* sw4 = (const float*)d_in[11];
    const float* sc4 = (const float*)d_in[12];
    const float* w1  = (const float*)d_in[13];
    const float* b1  = (const float*)d_in[14];
    const float* w2  = (const float*)d_in[15];
    const float* b2  = (const float*)d_in[16];
    const float* w3  = (const float*)d_in[17];
    const float* b3  = (const float*)d_in[18];

    float*  wsf = (float*)d_ws;
    ushort* wsu = (ushort*)d_ws;
    ushort* k1h = wsu + 110848;
    ushort* k1l = wsu + 120064;
    ushort* k2h = wsu + 129280;
    ushort* k2l = wsu + 143104;
    ushort* k3h = wsu + 156928;
    ushort* k3l = wsu + 179968;
    ushort* k4h = wsu + 203008;
    ushort* k4l = wsu + 249088;
    ushort* zph = wsu + 295168;
    ushort* zpl = wsu + 295248;
    ushort* A2h = wsu + 7864320;    // (B,1024,36)
    ushort* A2l = wsu + 12582912;
    ushort* A3h = wsu + 524288;     // (B,256,80)
    ushort* A3l = wsu + 3145728;
    ushort* A4h = wsu + 5767168;    // (B,2,256,80)
    ushort* A4l = wsu + 11010048;
    float* P3   = wsf + 9437184;    // 3x256x128x16 fp32
    float* P4   = wsf + 11534336;   // 3x256x128x32 fp32
    float* pooled = wsf + 262144;
    float* part1  = wsf + 524288;
    float* fc1o   = wsf + 2621440;
    float* part2  = wsf + 2883584;
    float* fc2o   = wsf + 3932160;

    prep_kernel<<<46, 256, 0, stream>>>(bw1, sw1, sc1, bw2, sw2, sc2,
                                        bw3, sw3, sc3, bw4, sw4, sc4,
                                        k1h, k1l, k2h, k2l, k3h, k3l, k4h, k4l,
                                        zph, zpl);

    conv1_fused<<<1024, 256, 0, stream>>>(x, k1h, k1l, A2h, A2l);
    conv2_strip4<<<1024, 256, 0, stream>>>(A2h, A2l, k2h, k2l, zph, zpl, A3h, A3l);
    conv34_part<1, 16><<<dim3(128, 2, 3), 256, 0, stream>>>(A3h, A3l, k3h, k3l,
                                                            zph, zpl, P3);
    conv3_reduce<<<dim3(128, 4), 256, 0, stream>>>(P3, A4h, A4l);
    conv34_part<2, 32><<<dim3(128, 2, 3), 256, 0, stream>>>(A4h, A4l, k4h, k4l,
                                                            zph, zpl, P4);
    conv4_reduce_pool<<<dim3(128, 2), 256, 0, stream>>>(P4, pooled);

    fc_big<8><<<dim3(32, 2, 8), 256, 0, stream>>>(pooled, w1, part1, 128, 2048, 2048);
    fc_reduce<8><<<1024, 256, 0, stream>>>(part1, b1, fc1o, 262144, 2048, 1);
    fc_big<8><<<dim3(16, 2, 8), 256, 0, stream>>>(fc1o, w2, part2, 128, 1024, 2048);
    fc_reduce<8><<<512, 256, 0, stream>>>(part2, b2, fc2o, 131072, 1024, 1);
    fc3_kernel<<<320, 256, 0, stream>>>(fc2o, w3, b3, (float*)d_out);
}

// Round 20
// 129.135 us; speedup vs baseline: 1.0389x; 1.0389x over previous
//
#include <hip/hip_runtime.h>
#include <hip/hip_bf16.h>

#define BATCH 128
#define AST 88  // conv34 padded-A LDS row stride in ushorts (176B, 16B-aligned)

typedef __attribute__((ext_vector_type(8))) short bf16x8;
typedef __attribute__((ext_vector_type(16))) float f32x16;

// ---------------------------------------------------------------------------
// Spline activation: act[0] = silu(x), act[1..8] = cubic B-spline bases
// ---------------------------------------------------------------------------
__device__ __forceinline__ void spline_acts(float xv, float act[9]) {
    act[0] = xv * (1.0f / (1.0f + __expf(-xv)));  // silu
    float g[12];
#pragma unroll
    for (int i = 0; i < 12; ++i) g[i] = (float)(i - 3) * 0.4f - 1.0f;
    float bb[11];
#pragma unroll
    for (int c = 0; c < 11; ++c) bb[c] = (xv >= g[c] && xv < g[c + 1]) ? 1.0f : 0.0f;
#pragma unroll
    for (int k = 1; k <= 3; ++k) {
#pragma unroll
        for (int c = 0; c + k < 11; ++c) {
            float left  = (xv - g[c]) * (1.0f / (g[c + k] - g[c])) * bb[c];
            float right = (g[c + k + 1] - xv) * (1.0f / (g[c + k + 1] - g[c + 1])) * bb[c + 1];
            bb[c] = left + right;
        }
    }
#pragma unroll
    for (int c = 0; c < 8; ++c) act[c + 1] = bb[c];
}

__device__ __constant__ float ZPAD[9] = {0.0f, 0.0f, 0.0f, 0.02083333333f,
                                         0.47916666667f, 0.47916666667f,
                                         0.02083333333f, 0.0f, 0.0f};

// bf16 hi/lo split via HW RNE converts
__device__ __forceinline__ void bf16split(float x, ushort& h, ushort& l) {
    __hip_bfloat16 bh = __float2bfloat16(x);
    float hf = __bfloat162float(bh);
    __hip_bfloat16 bl = __float2bfloat16(x - hf);
    h = *(ushort*)&bh;
    l = *(ushort*)&bl;
}

// packed conv weight value: f = cin*9 + tap, j = spline idx
__device__ __forceinline__ float wval(const float* bw, const float* sw, const float* sc,
                                      int F, int f, int j, int o) {
    if (j == 0) return bw[o * F + f];
    return sw[(o * F + f) * 8 + (j - 1)] * sc[o * F + f];
}

// ---------------------------------------------------------------------------
// prep: pack MFMA B-fragments (bf16 hi/lo) for all 4 conv layers + zp pattern.
// ---------------------------------------------------------------------------
__global__ __launch_bounds__(256) void prep_kernel(
    const float* __restrict__ bw1, const float* __restrict__ sw1, const float* __restrict__ sc1,
    const float* __restrict__ bw2, const float* __restrict__ sw2, const float* __restrict__ sc2,
    const float* __restrict__ bw3, const float* __restrict__ sw3, const float* __restrict__ sc3,
    const float* __restrict__ bw4, const float* __restrict__ sw4, const float* __restrict__ sc4,
    ushort* __restrict__ k1h, ushort* __restrict__ k1l,
    ushort* __restrict__ k2h, ushort* __restrict__ k2l,
    ushort* __restrict__ k3h, ushort* __restrict__ k3l,
    ushort* __restrict__ k4h, ushort* __restrict__ k4l,
    ushort* __restrict__ zph, ushort* __restrict__ zpl) {
    int i = blockIdx.x * 256 + threadIdx.x;
    if (i < 1152) {                            // conv1
        int l = i & 63, s = (i >> 6) & 1, t = i / 128;
#pragma unroll
        for (int e = 0; e < 8; ++e) {
            int k = s * 16 + ((l >> 5) * 8) + e, o = l & 31;
            float w = 0.f;
            if (k < 27 && o < 4) w = wval(bw1, sw1, sc1, 27, (k / 9) * 9 + t, k % 9, o);
            ushort h, lo; bf16split(w, h, lo);
            k1h[i * 8 + e] = h; k1l[i * 8 + e] = lo;
        }
    } else if (i < 2880) {                     // conv2
        int q = i - 1152;
        int l = q & 63, s = (q >> 6) % 3, t = q / 192;
#pragma unroll
        for (int e = 0; e < 8; ++e) {
            int k = s * 16 + ((l >> 5) * 8) + e, o = l & 31;
            float w = 0.f;
            if (k < 36 && o < 8) w = wval(bw2, sw2, sc2, 36, (k / 9) * 9 + t, k % 9, o);
            ushort h, lo; bf16split(w, h, lo);
            k2h[q * 8 + e] = h; k2l[q * 8 + e] = lo;
        }
    } else if (i < 5760) {                     // conv3
        int q = i - 2880;
        int l = q & 63, s = (q >> 6) % 5, t = q / 320;
#pragma unroll
        for (int e = 0; e < 8; ++e) {
            int k = s * 16 + ((l >> 5) * 8) + e, o = l & 31;
            float w = 0.f;
            if (k < 72 && o < 16) w = wval(bw3, sw3, sc3, 72, (k / 9) * 9 + t, k % 9, o);
            ushort h, lo; bf16split(w, h, lo);
            k3h[q * 8 + e] = h; k3l[q * 8 + e] = lo;
        }
    } else if (i < 11520) {                    // conv4
        int q = i - 5760;
        int l = q & 63, s = (q >> 6) % 5, t = (q / 320) % 9, p = q / 2880;
#pragma unroll
        for (int e = 0; e < 8; ++e) {
            int k = s * 16 + ((l >> 5) * 8) + e, o = l & 31;
            float w = 0.f;
            if (k < 72) w = wval(bw4, sw4, sc4, 144, (p * 8 + k / 9) * 9 + t, k % 9, o);
            ushort h, lo; bf16split(w, h, lo);
            k4h[q * 8 + e] = h; k4l[q * 8 + e] = lo;
        }
    } else if (i < 11600) {
        int c = i - 11520;
        ushort h, lo; bf16split(ZPAD[c % 9], h, lo);
        zph[c] = h; zpl[c] = lo;
    }
}

// ---------------------------------------------------------------------------
// conv1_fused v4 (verified): 4-row strips, ASTR=40, linear addressing.
// ---------------------------------------------------------------------------
__global__ __launch_bounds__(256) void conv1_fused(
    const float* __restrict__ x,
    const ushort* __restrict__ Bgh, const ushort* __restrict__ Bgl,
    ushort* __restrict__ Oh, ushort* __restrict__ Ol) {
    constexpr int ASTR = 40, KSTEPS = 2, NCO = 4;
    __shared__ ushort AH[204 * ASTR];
    __shared__ ushort AL[204 * ASTR];
    const int tid = threadIdx.x;
    const int b = blockIdx.x >> 3, strip = blockIdx.x & 7;
    const int r0 = strip * 4;
    const int lane = tid & 63, wv = tid >> 6;

    for (int px = tid; px < 204; px += 256) {
        int lr = px / 34, pc = px - lr * 34;
        int grow = r0 - 1 + lr, gc = pc - 1;
        bool inb = ((unsigned)grow < 32u) && ((unsigned)gc < 32u);
        unsigned rh[16], rl[16];
#pragma unroll
        for (int w = 0; w < 16; ++w) { rh[w] = 0u; rl[w] = 0u; }
        if (inb) {
            const float* xb = x + (size_t)b * 3072 + grow * 32 + gc;
#pragma unroll
            for (int cin = 0; cin < 3; ++cin) {
                float a9[9];
                spline_acts(xb[cin * 1024], a9);
#pragma unroll
                for (int j = 0; j < 9; ++j) {
                    ushort h, l2; bf16split(a9[j], h, l2);
                    int c = cin * 9 + j;
                    if (c & 1) { rh[c >> 1] |= (unsigned)h << 16; rl[c >> 1] |= (unsigned)l2 << 16; }
                    else       { rh[c >> 1] |= h;                  rl[c >> 1] |= l2; }
                }
            }
        } else {
#pragma unroll
            for (int c = 0; c < 27; ++c) {
                ushort h, l2; bf16split(ZPAD[c % 9], h, l2);
                if (c & 1) { rh[c >> 1] |= (unsigned)h << 16; rl[c >> 1] |= (unsigned)l2 << 16; }
                else       { rh[c >> 1] |= h;                  rl[c >> 1] |= l2; }
            }
        }
        unsigned* dh = (unsigned*)&AH[px * ASTR];
        unsigned* dl = (unsigned*)&AL[px * ASTR];
#pragma unroll
        for (int w = 0; w < 16; ++w) { dh[w] = rh[w]; dl[w] = rl[w]; }
    }
    __syncthreads();

    f32x16 acc;
#pragma unroll
    for (int i = 0; i < 16; ++i) acc[i] = 0.f;

    const int p0 = wv * 32 + (lane & 31);
    const int sp0 = ((p0 >> 5) + 1) * 34 + (p0 & 31) + 1;
    const int koff = (lane >> 5) * 8;

#pragma unroll 1
    for (int t = 0; t < 9; ++t) {
        const int dA = ((t / 3) - 1) * 34 + (t % 3) - 1;
#pragma unroll
        for (int s = 0; s < KSTEPS; ++s) {
            bf16x8 ah = *(const bf16x8*)(&AH[(sp0 + dA) * ASTR + s * 16 + koff]);
            bf16x8 al = *(const bf16x8*)(&AL[(sp0 + dA) * ASTR + s * 16 + koff]);
            bf16x8 bh = *(const bf16x8*)(Bgh + (size_t)((t * KSTEPS + s) * 64 + lane) * 8);
            bf16x8 bl = *(const bf16x8*)(Bgl + (size_t)((t * KSTEPS + s) * 64 + lane) * 8);
            acc = __builtin_amdgcn_mfma_f32_32x32x16_bf16(ah, bh, acc, 0, 0, 0);
            acc = __builtin_amdgcn_mfma_f32_32x32x16_bf16(ah, bl, acc, 0, 0, 0);
            acc = __builtin_amdgcn_mfma_f32_32x32x16_bf16(al, bh, acc, 0, 0, 0);
        }
    }
    __syncthreads();

    float* fl = (float*)AH;
    {
        int ccol = lane & 31;
        if (ccol < NCO) {
#pragma unroll
            for (int r = 0; r < 16; ++r) {
                int row = (r & 3) + 8 * (r >> 2) + 4 * (lane >> 5);
                fl[ccol * 129 + wv * 32 + row] = acc[r];
            }
        }
    }
    __syncthreads();

    unsigned* ubh = (unsigned*)AL;
    unsigned* ubl = (unsigned*)AH + 1032;
    {
        int px = tid >> 1, cop = tid & 1;
        unsigned rwh[9], rwl[9];
#pragma unroll
        for (int w = 0; w < 9; ++w) { rwh[w] = 0u; rwl[w] = 0u; }
#pragma unroll
        for (int e = 0; e < 2; ++e) {
            int co = cop * 2 + e;
            float a9[9];
            spline_acts(fl[co * 129 + px], a9);
#pragma unroll
            for (int j = 0; j < 9; ++j) {
                ushort h, l2; bf16split(a9[j], h, l2);
                int c = e * 9 + j;
                if (c & 1) { rwh[c >> 1] |= (unsigned)h << 16; rwl[c >> 1] |= (unsigned)l2 << 16; }
                else       { rwh[c >> 1] |= h;                  rwl[c >> 1] |= l2; }
            }
        }
#pragma unroll
        for (int w = 0; w < 9; ++w) {
            ubh[px * 18 + cop * 9 + w] = rwh[w];
            ubl[px * 18 + cop * 9 + w] = rwl[w];
        }
    }
    __syncthreads();
    size_t basew = ((size_t)b * 1024 + strip * 128) * 18;
    unsigned* goh = (unsigned*)Oh + basew;
    unsigned* gol = (unsigned*)Ol + basew;
#pragma unroll
    for (int e = 0; e < 9; ++e) {
        int q = e * 256 + tid;
        goh[q] = ubh[q];
        gol[q] = ubl[q];
    }
}

// ---------------------------------------------------------------------------
// conv2_strip (32x32, pool+spline epilogue) — verified round-18 structure.
// ---------------------------------------------------------------------------
template <int KG, int CHG, int CHL, int ASTR, int KSTEPS, int NCO>
__global__ __launch_bounds__(256) void conv2_strip(
    const ushort* __restrict__ Agh, const ushort* __restrict__ Agl,
    const ushort* __restrict__ Bgh, const ushort* __restrict__ Bgl,
    const ushort* __restrict__ zph, const ushort* __restrict__ zpl,
    ushort* __restrict__ Oh, ushort* __restrict__ Ol) {
    __shared__ ushort AH[340 * ASTR];
    __shared__ ushort AL[340 * ASTR];
    const int tid = threadIdx.x;
    const int b = blockIdx.x >> 2, strip = blockIdx.x & 3;
    const int r0 = strip * 8;
    const int lane = tid & 63, wv = tid >> 6;

    {
        const ushort* ash = Agh + (size_t)b * 1024 * KG;
        const ushort* asl = Agl + (size_t)b * 1024 * KG;
        for (int idx = tid; idx < 320 * CHL; idx += 256) {
            int pxl = idx / CHL, ch = idx - pxl * CHL;
            int lr = pxl >> 5, c = pxl & 31;
            int grow = r0 - 1 + lr;
            uint2 vh, vl;
            if (ch >= CHG) { vh = make_uint2(0u, 0u); vl = make_uint2(0u, 0u); }
            else if ((unsigned)grow < 32u) {
                vh = *(const uint2*)(ash + (size_t)(grow * 32 + c) * KG + ch * 4);
                vl = *(const uint2*)(asl + (size_t)(grow * 32 + c) * KG + ch * 4);
            } else {
                vh = *(const uint2*)(zph + ch * 4);
                vl = *(const uint2*)(zpl + ch * 4);
            }
            int spx = lr * 34 + c + 1;
            *(uint2*)(&AH[spx * ASTR + ch * 4]) = vh;
            *(uint2*)(&AL[spx * ASTR + ch * 4]) = vl;
        }
        for (int idx = tid; idx < 20 * CHL; idx += 256) {
            int sel = idx / CHL, ch = idx - sel * CHL;
            int lr = sel >> 1, c = (sel & 1) ? 33 : 0;
            int spx = lr * 34 + c;
            uint2 vh, vl;
            if (ch >= CHG) { vh = make_uint2(0u, 0u); vl = make_uint2(0u, 0u); }
            else { vh = *(const uint2*)(zph + ch * 4); vl = *(const uint2*)(zpl + ch * 4); }
            *(uint2*)(&AH[spx * ASTR + ch * 4]) = vh;
            *(uint2*)(&AL[spx * ASTR + ch * 4]) = vl;
        }
    }
    __syncthreads();

    f32x16 acc0, acc1;
#pragma unroll
    for (int i = 0; i < 16; ++i) { acc0[i] = 0.f; acc1[i] = 0.f; }

    const int p0 = wv * 64 + (lane & 31);
    const int sp0 = ((p0 >> 5) + 1) * 34 + (p0 & 31) + 1;
    const int sp1 = sp0 + 34;
    const int koff = (lane >> 5) * 8;

#pragma unroll 1
    for (int t = 0; t < 9; ++t) {
        const int dA = ((t / 3) - 1) * 34 + (t % 3) - 1;
#pragma unroll
        for (int s = 0; s < KSTEPS; ++s) {
            bf16x8 a0h = *(const bf16x8*)(&AH[(sp0 + dA) * ASTR + s * 16 + koff]);
            bf16x8 a0l = *(const bf16x8*)(&AL[(sp0 + dA) * ASTR + s * 16 + koff]);
            bf16x8 a1h = *(const bf16x8*)(&AH[(sp1 + dA) * ASTR + s * 16 + koff]);
            bf16x8 a1l = *(const bf16x8*)(&AL[(sp1 + dA) * ASTR + s * 16 + koff]);
            bf16x8 bh = *(const bf16x8*)(Bgh + (size_t)((t * KSTEPS + s) * 64 + lane) * 8);
            bf16x8 bl = *(const bf16x8*)(Bgl + (size_t)((t * KSTEPS + s) * 64 + lane) * 8);
            acc0 = __builtin_amdgcn_mfma_f32_32x32x16_bf16(a0h, bh, acc0, 0, 0, 0);
            acc1 = __builtin_amdgcn_mfma_f32_32x32x16_bf16(a1h, bh, acc1, 0, 0, 0);
            acc0 = __builtin_amdgcn_mfma_f32_32x32x16_bf16(a0h, bl, acc0, 0, 0, 0);
            acc1 = __builtin_amdgcn_mfma_f32_32x32x16_bf16(a1h, bl, acc1, 0, 0, 0);
            acc0 = __builtin_amdgcn_mfma_f32_32x32x16_bf16(a0l, bh, acc0, 0, 0, 0);
            acc1 = __builtin_amdgcn_mfma_f32_32x32x16_bf16(a1l, bh, acc1, 0, 0, 0);
        }
    }
    __syncthreads();

    float* fl = (float*)AH;
    {
        int ccol = lane & 31;
        if (ccol < NCO) {
#pragma unroll
            for (int r = 0; r < 16; ++r) {
                int row = (r & 3) + 8 * (r >> 2) + 4 * (lane >> 5);
                fl[ccol * 257 + wv * 64 + row] = acc0[r];
                fl[ccol * 257 + wv * 64 + 32 + row] = acc1[r];
            }
        }
    }
    __syncthreads();

    int cg = tid >> 6, pl = tid & 63;
    int phl = pl >> 4, pw = pl & 15;
    int base_m = (2 * phl) * 32 + 2 * pw;
    unsigned rwh[9], rwl[9];
#pragma unroll
    for (int w = 0; w < 9; ++w) { rwh[w] = 0u; rwl[w] = 0u; }
#pragma unroll
    for (int e = 0; e < 2; ++e) {
        int co = cg * 2 + e;
        const float* fb = fl + co * 257 + base_m;
        float m = fmaxf(fmaxf(fb[0], fb[1]), fmaxf(fb[32], fb[33]));
        float a9[9];
        spline_acts(m, a9);
#pragma unroll
        for (int j = 0; j < 9; ++j) {
            ushort h, l2; bf16split(a9[j], h, l2);
            int c = e * 9 + j;
            if (c & 1) { rwh[c >> 1] |= (unsigned)h << 16; rwl[c >> 1] |= (unsigned)l2 << 16; }
            else       { rwh[c >> 1] |= h;                  rwl[c >> 1] |= l2; }
        }
    }
    unsigned* ubh = (unsigned*)AL;
    unsigned* ubl = (unsigned*)AL + 2560;
#pragma unroll
    for (int w = 0; w < 9; ++w) {
        ubh[pl * 40 + cg * 9 + w] = rwh[w];
        ubl[pl * 40 + cg * 9 + w] = rwl[w];
    }
    if (cg == 3) {
#pragma unroll
        for (int w = 0; w < 4; ++w) { ubh[pl * 40 + 36 + w] = 0u; ubl[pl * 40 + 36 + w] = 0u; }
    }
    __syncthreads();
    size_t base = ((size_t)b * 256 + strip * 64) * 80;
    const ushort* sbh = (const ushort*)ubh;
    const ushort* sbl = (const ushort*)ubl;
#pragma unroll
    for (int e = 0; e < 3; ++e) {
        int q = e * 256 + tid;
        if (q < 640) {
            *(uint4*)(Oh + base + q * 8) = *(const uint4*)(sbh + q * 8);
            *(uint4*)(Ol + base + q * 8) = *(const uint4*)(sbl + q * 8);
        }
    }
}

// ---------------------------------------------------------------------------
// conv34_part: split-K MFMA partial, z = dh-group (3); cin-phases looped.
// ---------------------------------------------------------------------------
template <int NPH, int NCO>
__global__ __launch_bounds__(256) void conv34_part(
    const ushort* __restrict__ Agh, const ushort* __restrict__ Agl,
    const ushort* __restrict__ Bgh, const ushort* __restrict__ Bgl,
    const ushort* __restrict__ zph, const ushort* __restrict__ zpl,
    float* __restrict__ P) {
    __shared__ ushort AH[144 * AST];
    __shared__ ushort AL[144 * AST];
    const int tid = threadIdx.x;
    const int b = blockIdx.x, half = blockIdx.y, g = blockIdx.z;
    const int r0 = half * 8;
    const int lane = tid & 63, wv = tid >> 6;

    f32x16 acc;
#pragma unroll
    for (int i = 0; i < 16; ++i) acc[i] = 0.f;

    const int m = wv * 32 + (lane & 31);
    const int sbase = (m >> 4) * 18 + (m & 15);
    const int koff = (lane >> 5) * 8;

#pragma unroll 1
    for (int p = 0; p < NPH; ++p) {
        if (p) __syncthreads();
        const ushort* ash = Agh + ((size_t)b * NPH + p) * 256 * 80;
        const ushort* asl = Agl + ((size_t)b * NPH + p) * 256 * 80;
#pragma unroll
        for (int e = 0; e < 6; ++e) {
            int idx = e * 256 + tid;
            if (idx < 1440) {
                int px = idx / 10, ch = idx - px * 10;
                int pr = px / 18, pc = px - pr * 18;
                int r = r0 - 1 + g + pr, c = pc - 1;
                bool inb = ((unsigned)r < 16u) && ((unsigned)c < 16u);
                uint4 vh, vl;
                if (inb) {
                    vh = *(const uint4*)(ash + (size_t)(r * 16 + c) * 80 + ch * 8);
                    vl = *(const uint4*)(asl + (size_t)(r * 16 + c) * 80 + ch * 8);
                } else {
                    vh = *(const uint4*)(zph + ch * 8);
                    vl = *(const uint4*)(zpl + ch * 8);
                }
                *(uint4*)(&AH[px * AST + ch * 8]) = vh;
                *(uint4*)(&AL[px * AST + ch * 8]) = vl;
            }
        }
        __syncthreads();

        const ushort* bsh = Bgh + (size_t)p * 2880 * 8;
        const ushort* bsl = Bgl + (size_t)p * 2880 * 8;
#pragma unroll
        for (int dw = 0; dw < 3; ++dw) {
            const int t = g * 3 + dw;
#pragma unroll
            for (int s = 0; s < 5; ++s) {
                bf16x8 ah = *(const bf16x8*)(&AH[(sbase + dw) * AST + s * 16 + koff]);
                bf16x8 al = *(const bf16x8*)(&AL[(sbase + dw) * AST + s * 16 + koff]);
                bf16x8 bh = *(const bf16x8*)(bsh + (size_t)((t * 5 + s) * 64 + lane) * 8);
                bf16x8 bl = *(const bf16x8*)(bsl + (size_t)((t * 5 + s) * 64 + lane) * 8);
                acc = __builtin_amdgcn_mfma_f32_32x32x16_bf16(ah, bh, acc, 0, 0, 0);
                acc = __builtin_amdgcn_mfma_f32_32x32x16_bf16(ah, bl, acc, 0, 0, 0);
                acc = __builtin_amdgcn_mfma_f32_32x32x16_bf16(al, bh, acc, 0, 0, 0);
            }
        }
    }

    int co = lane & 31;
    if (co < NCO) {
        float* pb = P + ((size_t)(g * 256 + b * 2 + half) * 128) * NCO;
#pragma unroll
        for (int r = 0; r < 16; ++r) {
            int px = wv * 32 + (r & 3) + 8 * (r >> 2) + 4 * (lane >> 5);
            pb[px * NCO + co] = acc[r];
        }
    }
}

// ---------------------------------------------------------------------------
// conv3_reduce v3: block = (b, px-quarter), all 16 couts, 64 px.
// ---------------------------------------------------------------------------
__global__ __launch_bounds__(256) void conv3_reduce(const float* __restrict__ P3,
                                                    ushort* __restrict__ A4h,
                                                    ushort* __restrict__ A4l) {
    __shared__ ushort SBH[2][64 * 80];
    __shared__ ushort SBL[2][64 * 80];
    int b = blockIdx.x, pxq = blockIdx.y;
    int t = threadIdx.x;
    int co = t & 15, pxg = t >> 4;
#pragma unroll
    for (int q = 0; q < 4; ++q) {
        int lpx64 = pxg * 4 + q;
        int px = pxq * 64 + lpx64;
        int bh = b * 2 + (px >> 7), lpx = px & 127;
        float s = 0.f;
#pragma unroll
        for (int zz = 0; zz < 3; ++zz)
            s += P3[((size_t)(zz * 256 + bh) * 128 + lpx) * 16 + co];
        float a9[9];
        spline_acts(s, a9);
        int ph = co >> 3, c8 = co & 7;
#pragma unroll
        for (int j = 0; j < 9; ++j) {
            ushort h, l2; bf16split(a9[j], h, l2);
            SBH[ph][lpx64 * 80 + c8 * 9 + j] = h;
            SBL[ph][lpx64 * 80 + c8 * 9 + j] = l2;
        }
        if (c8 == 7) {
#pragma unroll
            for (int w = 0; w < 8; ++w) {
                SBH[ph][lpx64 * 80 + 72 + w] = 0;
                SBL[ph][lpx64 * 80 + 72 + w] = 0;
            }
        }
    }
    __syncthreads();
#pragma unroll
    for (int ph = 0; ph < 2; ++ph) {
        size_t base = ((size_t)(b * 2 + ph) * 256 + pxq * 64) * 80;
#pragma unroll
        for (int e = 0; e < 3; ++e) {
            int q = e * 256 + t;
            if (q < 640) {
                *(uint4*)(A4h + base + q * 8) = *(const uint4*)(&SBH[ph][q * 8]);
                *(uint4*)(A4l + base + q * 8) = *(const uint4*)(&SBL[ph][q * 8]);
            }
        }
    }
}

// ---------------------------------------------------------------------------
// conv4_reduce_pool v2: block = (b, half); sum 3 partials + 2x2 pool.
// ---------------------------------------------------------------------------
__global__ __launch_bounds__(256) void conv4_reduce_pool(const float* __restrict__ P4,
                                                         float* __restrict__ pooled) {
    __shared__ float SM[32 * 33];
    int b = blockIdx.x, half = blockIdx.y;
    int t = threadIdx.x;
    int co = t & 31, pg = t >> 5;
    int bh = b * 2 + half;
#pragma unroll
    for (int q = 0; q < 4; ++q) {
        int pp = pg * 4 + q;
        int lr = pp >> 3, pc = pp & 7;
        int px00 = (2 * lr) * 16 + 2 * pc;
        float s00 = 0.f, s01 = 0.f, s10 = 0.f, s11 = 0.f;
#pragma unroll
        for (int zz = 0; zz < 3; ++zz) {
            const float* pb = P4 + ((size_t)(zz * 256 + bh) * 128) * 32 + co;
            s00 += pb[(size_t)px00 * 32];
            s01 += pb[(size_t)(px00 + 1) * 32];
            s10 += pb[(size_t)(px00 + 16) * 32];
            s11 += pb[(size_t)(px00 + 17) * 32];
        }
        SM[co * 33 + pp] = fmaxf(fmaxf(s00, s01), fmaxf(s10, s11));
    }
    __syncthreads();
#pragma unroll
    for (int e = 0; e < 4; ++e) {
        int idx = e * 256 + t;
        int co2 = idx >> 5, pp2 = idx & 31;
        int lr2 = pp2 >> 3, pc2 = pp2 & 7;
        pooled[(size_t)b * 2048 + co2 * 64 + (half * 4 + lr2) * 8 + pc2] = SM[co2 * 33 + pp2];
    }
}

// ---------------------------------------------------------------------------
// fc_big: 64x64 tile, 4x4/thread, K_TILE=32, split-K; float4 global staging.
// ---------------------------------------------------------------------------
template <int SPLIT>
__global__ __launch_bounds__(256) void fc_big(const float* __restrict__ A,
                                              const float* __restrict__ Wt,
                                              float* __restrict__ part,
                                              int M, int N, int K) {
    __shared__ float As[32][68];
    __shared__ float Ws[32][68];
    const int tid = threadIdx.x;
    const int tx = tid & 15, ty = tid >> 4;
    const int bm = blockIdx.y * 64, bn = blockIdx.x * 64;
    const int kc = K / SPLIT;
    const int kbeg = blockIdx.z * kc;
    float acc[4][4] = {};
    for (int k0 = kbeg; k0 < kbeg + kc; k0 += 32) {
#pragma unroll
        for (int e = 0; e < 2; ++e) {
            int q = e * 256 + tid;
            int r = q >> 3, k4 = (q & 7) * 4;
            float4 av = *(const float4*)&A[(size_t)(bm + r) * K + k0 + k4];
            float4 wv = *(const float4*)&Wt[(size_t)(bn + r) * K + k0 + k4];
            As[k4 + 0][r] = av.x; As[k4 + 1][r] = av.y;
            As[k4 + 2][r] = av.z; As[k4 + 3][r] = av.w;
            Ws[k4 + 0][r] = wv.x; Ws[k4 + 1][r] = wv.y;
            Ws[k4 + 2][r] = wv.z; Ws[k4 + 3][r] = wv.w;
        }
        __syncthreads();
#pragma unroll
        for (int kk = 0; kk < 32; ++kk) {
            float4 av = *(const float4*)(&As[kk][ty * 4]);
            float4 wv = *(const float4*)(&Ws[kk][tx * 4]);
            acc[0][0] = fmaf(av.x, wv.x, acc[0][0]);
            acc[0][1] = fmaf(av.x, wv.y, acc[0][1]);
            acc[0][2] = fmaf(av.x, wv.z, acc[0][2]);
            acc[0][3] = fmaf(av.x, wv.w, acc[0][3]);
            acc[1][0] = fmaf(av.y, wv.x, acc[1][0]);
            acc[1][1] = fmaf(av.y, wv.y, acc[1][1]);
            acc[1][2] = fmaf(av.y, wv.z, acc[1][2]);
            acc[1][3] = fmaf(av.y, wv.w, acc[1][3]);
            acc[2][0] = fmaf(av.z, wv.x, acc[2][0]);
            acc[2][1] = fmaf(av.z, wv.y, acc[2][1]);
            acc[2][2] = fmaf(av.z, wv.z, acc[2][2]);
            acc[2][3] = fmaf(av.z, wv.w, acc[2][3]);
            acc[3][0] = fmaf(av.w, wv.x, acc[3][0]);
            acc[3][1] = fmaf(av.w, wv.y, acc[3][1]);
            acc[3][2] = fmaf(av.w, wv.z, acc[3][2]);
            acc[3][3] = fmaf(av.w, wv.w, acc[3][3]);
        }
        __syncthreads();
    }
    float* p = part + (size_t)blockIdx.z * M * N;
#pragma unroll
    for (int i = 0; i < 4; ++i) {
        float4 v = make_float4(acc[i][0], acc[i][1], acc[i][2], acc[i][3]);
        *(float4*)&p[(size_t)(bm + ty * 4 + i) * N + (bn + tx * 4)] = v;
    }
}

template <int SPLIT>
__global__ void fc_reduce(const float* __restrict__ part, const float* __restrict__ bias,
                          float* __restrict__ C, int MN, int N, int relu) {
    int i = blockIdx.x * 256 + threadIdx.x;
    if (i >= MN) return;
    float s = bias[i % N];
#pragma unroll
    for (int z = 0; z < SPLIT; ++z) s += part[(size_t)z * MN + i];
    C[i] = relu ? fmaxf(s, 0.f) : s;
}

__global__ __launch_bounds__(256) void fc3_kernel(const float* __restrict__ A,
                                                  const float* __restrict__ Wt,
                                                  const float* __restrict__ bias,
                                                  float* __restrict__ C) {
    int gid = blockIdx.x * 256 + threadIdx.x;
    int wid = gid >> 6;
    int lane = gid & 63;
    int m = wid / 10, n = wid - m * 10;
    const float4* a = (const float4*)(A + (size_t)m * 1024);
    const float4* w = (const float4*)(Wt + (size_t)n * 1024);
    float s = 0.f;
#pragma unroll
    for (int it = 0; it < 4; ++it) {
        float4 av = a[it * 64 + lane];
        float4 wv = w[it * 64 + lane];
        s += av.x * wv.x + av.y * wv.y + av.z * wv.z + av.w * wv.w;
    }
#pragma unroll
    for (int off = 32; off; off >>= 1) s += __shfl_xor(s, off);
    if (lane == 0) C[wid] = s + bias[n];
}

// ---------------------------------------------------------------------------
extern "C" void kernel_launch(void* const* d_in, const int* in_sizes, int n_in,
                              void* d_out, int out_size, void* d_ws, size_t ws_size,
                              hipStream_t stream) {
    const float* x   = (const float*)d_in[0];
    const float* bw1 = (const float*)d_in[1];
    const float* sw1 = (const float*)d_in[2];
    const float* sc1 = (const float*)d_in[3];
    const float* bw2 = (const float*)d_in[4];
    const float* sw2 = (const float*)d_in[5];
    const float* sc2 = (const float*)d_in[6];
    const float* bw3 = (const float*)d_in[7];
    const float* sw3 = (const float*)d_in[8];
    const float* sc3 = (const float*)d_in[9];
    const float* bw4 = (const float*)d_in[10];
    const float* sw4 = (const float*)d_in[11];
    const float* sc4 = (const float*)d_in[12];
    const float* w1  = (const float*)d_in[13];
    const float* b1  = (const float*)d_in[14];
    const float* w2  = (const float*)d_in[15];
    const float* b2  = (const float*)d_in[16];
    const float* w3  = (const float*)d_in[17];
    const float* b3  = (const float*)d_in[18];

    float*  wsf = (float*)d_ws;
    ushort* wsu = (ushort*)d_ws;
    ushort* k1h = wsu + 110848;
    ushort* k1l = wsu + 120064;
    ushort* k2h = wsu + 129280;
    ushort* k2l = wsu + 143104;
    ushort* k3h = wsu + 156928;
    ushort* k3l = wsu + 179968;
    ushort* k4h = wsu + 203008;
    ushort* k4l = wsu + 249088;
    ushort* zph = wsu + 295168;
    ushort* zpl = wsu + 295248;
    ushort* A2h = wsu + 7864320;    // (B,1024,36)
    ushort* A2l = wsu + 12582912;
    ushort* A3h = wsu + 524288;     // (B,256,80)
    ushort* A3l = wsu + 3145728;
    ushort* A4h = wsu + 5767168;    // (B,2,256,80)
    ushort* A4l = wsu + 11010048;
    float* P3   = wsf + 9437184;    // 3x256x128x16 fp32
    float* P4   = wsf + 11534336;   // 3x256x128x32 fp32
    float* pooled = wsf + 262144;
    float* part1  = wsf + 524288;
    float* fc1o   = wsf + 2621440;
    float* part2  = wsf + 2883584;
    float* fc2o   = wsf + 3932160;

    prep_kernel<<<46, 256, 0, stream>>>(bw1, sw1, sc1, bw2, sw2, sc2,
                                        bw3, sw3, sc3, bw4, sw4, sc4,
                                        k1h, k1l, k2h, k2l, k3h, k3l, k4h, k4l,
                                        zph, zpl);

    conv1_fused<<<1024, 256, 0, stream>>>(x, k1h, k1l, A2h, A2l);
    conv2_strip<36, 9, 12, 56, 3, 8><<<512, 256, 0, stream>>>(A2h, A2l, k2h, k2l,
                                                              zph, zpl, A3h, A3l);
    conv34_part<1, 16><<<dim3(128, 2, 3), 256, 0, stream>>>(A3h, A3l, k3h, k3l,
                                                            zph, zpl, P3);
    conv3_reduce<<<dim3(128, 4), 256, 0, stream>>>(P3, A4h, A4l);
    conv34_part<2, 32><<<dim3(128, 2, 3), 256, 0, stream>>>(A4h, A4l, k4h, k4l,
                                                            zph, zpl, P4);
    conv4_reduce_pool<<<dim3(128, 2), 256, 0, stream>>>(P4, pooled);

    fc_big<8><<<dim3(32, 2, 8), 256, 0, stream>>>(pooled, w1, part1, 128, 2048, 2048);
    fc_reduce<8><<<1024, 256, 0, stream>>>(part1, b1, fc1o, 262144, 2048, 1);
    fc_big<8><<<dim3(16, 2, 8), 256, 0, stream>>>(fc1o, w2, part2, 128, 1024, 2048);
    fc_reduce<8><<<512, 256, 0, stream>>>(part2, b2, fc2o, 131072, 1024, 1);
    fc3_kernel<<<320, 256, 0, stream>>>(fc2o, w3, b3, (float*)d_out);
}

// Round 21
// 128.737 us; speedup vs baseline: 1.0421x; 1.0031x over previous
//
#include <hip/hip_runtime.h>
#include <hip/hip_bf16.h>

#define BATCH 128
#define AST 88  // conv34 padded-A LDS row stride in ushorts (176B, 16B-aligned)

typedef __attribute__((ext_vector_type(8))) short bf16x8;
typedef __attribute__((ext_vector_type(16))) float f32x16;

// ---------------------------------------------------------------------------
// Spline activation: act[0] = silu(x), act[1..8] = cubic B-spline bases
// ---------------------------------------------------------------------------
__device__ __forceinline__ void spline_acts(float xv, float act[9]) {
    act[0] = xv * (1.0f / (1.0f + __expf(-xv)));  // silu
    float g[12];
#pragma unroll
    for (int i = 0; i < 12; ++i) g[i] = (float)(i - 3) * 0.4f - 1.0f;
    float bb[11];
#pragma unroll
    for (int c = 0; c < 11; ++c) bb[c] = (xv >= g[c] && xv < g[c + 1]) ? 1.0f : 0.0f;
#pragma unroll
    for (int k = 1; k <= 3; ++k) {
#pragma unroll
        for (int c = 0; c + k < 11; ++c) {
            float left  = (xv - g[c]) * (1.0f / (g[c + k] - g[c])) * bb[c];
            float right = (g[c + k + 1] - xv) * (1.0f / (g[c + k + 1] - g[c + 1])) * bb[c + 1];
            bb[c] = left + right;
        }
    }
#pragma unroll
    for (int c = 0; c < 8; ++c) act[c + 1] = bb[c];
}

__device__ __constant__ float ZPAD[9] = {0.0f, 0.0f, 0.0f, 0.02083333333f,
                                         0.47916666667f, 0.47916666667f,
                                         0.02083333333f, 0.0f, 0.0f};

// bf16 hi/lo split via HW RNE converts
__device__ __forceinline__ void bf16split(float x, ushort& h, ushort& l) {
    __hip_bfloat16 bh = __float2bfloat16(x);
    float hf = __bfloat162float(bh);
    __hip_bfloat16 bl = __float2bfloat16(x - hf);
    h = *(ushort*)&bh;
    l = *(ushort*)&bl;
}

// packed conv weight value: f = cin*9 + tap, j = spline idx
__device__ __forceinline__ float wval(const float* bw, const float* sw, const float* sc,
                                      int F, int f, int j, int o) {
    if (j == 0) return bw[o * F + f];
    return sw[(o * F + f) * 8 + (j - 1)] * sc[o * F + f];
}

// ---------------------------------------------------------------------------
// prep: pack MFMA B-fragments (bf16 hi/lo) for all 4 conv layers + zp pattern.
// ---------------------------------------------------------------------------
__global__ __launch_bounds__(256) void prep_kernel(
    const float* __restrict__ bw1, const float* __restrict__ sw1, const float* __restrict__ sc1,
    const float* __restrict__ bw2, const float* __restrict__ sw2, const float* __restrict__ sc2,
    const float* __restrict__ bw3, const float* __restrict__ sw3, const float* __restrict__ sc3,
    const float* __restrict__ bw4, const float* __restrict__ sw4, const float* __restrict__ sc4,
    ushort* __restrict__ k1h, ushort* __restrict__ k1l,
    ushort* __restrict__ k2h, ushort* __restrict__ k2l,
    ushort* __restrict__ k3h, ushort* __restrict__ k3l,
    ushort* __restrict__ k4h, ushort* __restrict__ k4l,
    ushort* __restrict__ zph, ushort* __restrict__ zpl) {
    int i = blockIdx.x * 256 + threadIdx.x;
    if (i < 1152) {                            // conv1
        int l = i & 63, s = (i >> 6) & 1, t = i / 128;
#pragma unroll
        for (int e = 0; e < 8; ++e) {
            int k = s * 16 + ((l >> 5) * 8) + e, o = l & 31;
            float w = 0.f;
            if (k < 27 && o < 4) w = wval(bw1, sw1, sc1, 27, (k / 9) * 9 + t, k % 9, o);
            ushort h, lo; bf16split(w, h, lo);
            k1h[i * 8 + e] = h; k1l[i * 8 + e] = lo;
        }
    } else if (i < 2880) {                     // conv2
        int q = i - 1152;
        int l = q & 63, s = (q >> 6) % 3, t = q / 192;
#pragma unroll
        for (int e = 0; e < 8; ++e) {
            int k = s * 16 + ((l >> 5) * 8) + e, o = l & 31;
            float w = 0.f;
            if (k < 36 && o < 8) w = wval(bw2, sw2, sc2, 36, (k / 9) * 9 + t, k % 9, o);
            ushort h, lo; bf16split(w, h, lo);
            k2h[q * 8 + e] = h; k2l[q * 8 + e] = lo;
        }
    } else if (i < 5760) {                     // conv3
        int q = i - 2880;
        int l = q & 63, s = (q >> 6) % 5, t = q / 320;
#pragma unroll
        for (int e = 0; e < 8; ++e) {
            int k = s * 16 + ((l >> 5) * 8) + e, o = l & 31;
            float w = 0.f;
            if (k < 72 && o < 16) w = wval(bw3, sw3, sc3, 72, (k / 9) * 9 + t, k % 9, o);
            ushort h, lo; bf16split(w, h, lo);
            k3h[q * 8 + e] = h; k3l[q * 8 + e] = lo;
        }
    } else if (i < 11520) {                    // conv4
        int q = i - 5760;
        int l = q & 63, s = (q >> 6) % 5, t = (q / 320) % 9, p = q / 2880;
#pragma unroll
        for (int e = 0; e < 8; ++e) {
            int k = s * 16 + ((l >> 5) * 8) + e, o = l & 31;
            float w = 0.f;
            if (k < 72) w = wval(bw4, sw4, sc4, 144, (p * 8 + k / 9) * 9 + t, k % 9, o);
            ushort h, lo; bf16split(w, h, lo);
            k4h[q * 8 + e] = h; k4l[q * 8 + e] = lo;
        }
    } else if (i < 11600) {
        int c = i - 11520;
        ushort h, lo; bf16split(ZPAD[c % 9], h, lo);
        zph[c] = h; zpl[c] = lo;
    }
}

// ---------------------------------------------------------------------------
// conv1_fused v4 (verified): 4-row strips, ASTR=40, linear addressing.
// ---------------------------------------------------------------------------
__global__ __launch_bounds__(256) void conv1_fused(
    const float* __restrict__ x,
    const ushort* __restrict__ Bgh, const ushort* __restrict__ Bgl,
    ushort* __restrict__ Oh, ushort* __restrict__ Ol) {
    constexpr int ASTR = 40, KSTEPS = 2, NCO = 4;
    __shared__ ushort AH[204 * ASTR];
    __shared__ ushort AL[204 * ASTR];
    const int tid = threadIdx.x;
    const int b = blockIdx.x >> 3, strip = blockIdx.x & 7;
    const int r0 = strip * 4;
    const int lane = tid & 63, wv = tid >> 6;

    for (int px = tid; px < 204; px += 256) {
        int lr = px / 34, pc = px - lr * 34;
        int grow = r0 - 1 + lr, gc = pc - 1;
        bool inb = ((unsigned)grow < 32u) && ((unsigned)gc < 32u);
        unsigned rh[16], rl[16];
#pragma unroll
        for (int w = 0; w < 16; ++w) { rh[w] = 0u; rl[w] = 0u; }
        if (inb) {
            const float* xb = x + (size_t)b * 3072 + grow * 32 + gc;
#pragma unroll
            for (int cin = 0; cin < 3; ++cin) {
                float a9[9];
                spline_acts(xb[cin * 1024], a9);
#pragma unroll
                for (int j = 0; j < 9; ++j) {
                    ushort h, l2; bf16split(a9[j], h, l2);
                    int c = cin * 9 + j;
                    if (c & 1) { rh[c >> 1] |= (unsigned)h << 16; rl[c >> 1] |= (unsigned)l2 << 16; }
                    else       { rh[c >> 1] |= h;                  rl[c >> 1] |= l2; }
                }
            }
        } else {
#pragma unroll
            for (int c = 0; c < 27; ++c) {
                ushort h, l2; bf16split(ZPAD[c % 9], h, l2);
                if (c & 1) { rh[c >> 1] |= (unsigned)h << 16; rl[c >> 1] |= (unsigned)l2 << 16; }
                else       { rh[c >> 1] |= h;                  rl[c >> 1] |= l2; }
            }
        }
        unsigned* dh = (unsigned*)&AH[px * ASTR];
        unsigned* dl = (unsigned*)&AL[px * ASTR];
#pragma unroll
        for (int w = 0; w < 16; ++w) { dh[w] = rh[w]; dl[w] = rl[w]; }
    }
    __syncthreads();

    f32x16 acc;
#pragma unroll
    for (int i = 0; i < 16; ++i) acc[i] = 0.f;

    const int p0 = wv * 32 + (lane & 31);
    const int sp0 = ((p0 >> 5) + 1) * 34 + (p0 & 31) + 1;
    const int koff = (lane >> 5) * 8;

#pragma unroll 1
    for (int t = 0; t < 9; ++t) {
        const int dA = ((t / 3) - 1) * 34 + (t % 3) - 1;
#pragma unroll
        for (int s = 0; s < KSTEPS; ++s) {
            bf16x8 ah = *(const bf16x8*)(&AH[(sp0 + dA) * ASTR + s * 16 + koff]);
            bf16x8 al = *(const bf16x8*)(&AL[(sp0 + dA) * ASTR + s * 16 + koff]);
            bf16x8 bh = *(const bf16x8*)(Bgh + (size_t)((t * KSTEPS + s) * 64 + lane) * 8);
            bf16x8 bl = *(const bf16x8*)(Bgl + (size_t)((t * KSTEPS + s) * 64 + lane) * 8);
            acc = __builtin_amdgcn_mfma_f32_32x32x16_bf16(ah, bh, acc, 0, 0, 0);
            acc = __builtin_amdgcn_mfma_f32_32x32x16_bf16(ah, bl, acc, 0, 0, 0);
            acc = __builtin_amdgcn_mfma_f32_32x32x16_bf16(al, bh, acc, 0, 0, 0);
        }
    }
    __syncthreads();

    float* fl = (float*)AH;
    {
        int ccol = lane & 31;
        if (ccol < NCO) {
#pragma unroll
            for (int r = 0; r < 16; ++r) {
                int row = (r & 3) + 8 * (r >> 2) + 4 * (lane >> 5);
                fl[ccol * 129 + wv * 32 + row] = acc[r];
            }
        }
    }
    __syncthreads();

    unsigned* ubh = (unsigned*)AL;
    unsigned* ubl = (unsigned*)AH + 1032;
    {
        int px = tid >> 1, cop = tid & 1;
        unsigned rwh[9], rwl[9];
#pragma unroll
        for (int w = 0; w < 9; ++w) { rwh[w] = 0u; rwl[w] = 0u; }
#pragma unroll
        for (int e = 0; e < 2; ++e) {
            int co = cop * 2 + e;
            float a9[9];
            spline_acts(fl[co * 129 + px], a9);
#pragma unroll
            for (int j = 0; j < 9; ++j) {
                ushort h, l2; bf16split(a9[j], h, l2);
                int c = e * 9 + j;
                if (c & 1) { rwh[c >> 1] |= (unsigned)h << 16; rwl[c >> 1] |= (unsigned)l2 << 16; }
                else       { rwh[c >> 1] |= h;                  rwl[c >> 1] |= l2; }
            }
        }
#pragma unroll
        for (int w = 0; w < 9; ++w) {
            ubh[px * 18 + cop * 9 + w] = rwh[w];
            ubl[px * 18 + cop * 9 + w] = rwl[w];
        }
    }
    __syncthreads();
    size_t basew = ((size_t)b * 1024 + strip * 128) * 18;
    unsigned* goh = (unsigned*)Oh + basew;
    unsigned* gol = (unsigned*)Ol + basew;
#pragma unroll
    for (int e = 0; e < 9; ++e) {
        int q = e * 256 + tid;
        goh[q] = ubh[q];
        gol[q] = ubl[q];
    }
}

// ---------------------------------------------------------------------------
// conv2_strip (32x32, pool+spline epilogue) — verified round-18 structure.
// ---------------------------------------------------------------------------
template <int KG, int CHG, int CHL, int ASTR, int KSTEPS, int NCO>
__global__ __launch_bounds__(256) void conv2_strip(
    const ushort* __restrict__ Agh, const ushort* __restrict__ Agl,
    const ushort* __restrict__ Bgh, const ushort* __restrict__ Bgl,
    const ushort* __restrict__ zph, const ushort* __restrict__ zpl,
    ushort* __restrict__ Oh, ushort* __restrict__ Ol) {
    __shared__ ushort AH[340 * ASTR];
    __shared__ ushort AL[340 * ASTR];
    const int tid = threadIdx.x;
    const int b = blockIdx.x >> 2, strip = blockIdx.x & 3;
    const int r0 = strip * 8;
    const int lane = tid & 63, wv = tid >> 6;

    {
        const ushort* ash = Agh + (size_t)b * 1024 * KG;
        const ushort* asl = Agl + (size_t)b * 1024 * KG;
        for (int idx = tid; idx < 320 * CHL; idx += 256) {
            int pxl = idx / CHL, ch = idx - pxl * CHL;
            int lr = pxl >> 5, c = pxl & 31;
            int grow = r0 - 1 + lr;
            uint2 vh, vl;
            if (ch >= CHG) { vh = make_uint2(0u, 0u); vl = make_uint2(0u, 0u); }
            else if ((unsigned)grow < 32u) {
                vh = *(const uint2*)(ash + (size_t)(grow * 32 + c) * KG + ch * 4);
                vl = *(const uint2*)(asl + (size_t)(grow * 32 + c) * KG + ch * 4);
            } else {
                vh = *(const uint2*)(zph + ch * 4);
                vl = *(const uint2*)(zpl + ch * 4);
            }
            int spx = lr * 34 + c + 1;
            *(uint2*)(&AH[spx * ASTR + ch * 4]) = vh;
            *(uint2*)(&AL[spx * ASTR + ch * 4]) = vl;
        }
        for (int idx = tid; idx < 20 * CHL; idx += 256) {
            int sel = idx / CHL, ch = idx - sel * CHL;
            int lr = sel >> 1, c = (sel & 1) ? 33 : 0;
            int spx = lr * 34 + c;
            uint2 vh, vl;
            if (ch >= CHG) { vh = make_uint2(0u, 0u); vl = make_uint2(0u, 0u); }
            else { vh = *(const uint2*)(zph + ch * 4); vl = *(const uint2*)(zpl + ch * 4); }
            *(uint2*)(&AH[spx * ASTR + ch * 4]) = vh;
            *(uint2*)(&AL[spx * ASTR + ch * 4]) = vl;
        }
    }
    __syncthreads();

    f32x16 acc0, acc1;
#pragma unroll
    for (int i = 0; i < 16; ++i) { acc0[i] = 0.f; acc1[i] = 0.f; }

    const int p0 = wv * 64 + (lane & 31);
    const int sp0 = ((p0 >> 5) + 1) * 34 + (p0 & 31) + 1;
    const int sp1 = sp0 + 34;
    const int koff = (lane >> 5) * 8;

#pragma unroll 1
    for (int t = 0; t < 9; ++t) {
        const int dA = ((t / 3) - 1) * 34 + (t % 3) - 1;
#pragma unroll
        for (int s = 0; s < KSTEPS; ++s) {
            bf16x8 a0h = *(const bf16x8*)(&AH[(sp0 + dA) * ASTR + s * 16 + koff]);
            bf16x8 a0l = *(const bf16x8*)(&AL[(sp0 + dA) * ASTR + s * 16 + koff]);
            bf16x8 a1h = *(const bf16x8*)(&AH[(sp1 + dA) * ASTR + s * 16 + koff]);
            bf16x8 a1l = *(const bf16x8*)(&AL[(sp1 + dA) * ASTR + s * 16 + koff]);
            bf16x8 bh = *(const bf16x8*)(Bgh + (size_t)((t * KSTEPS + s) * 64 + lane) * 8);
            bf16x8 bl = *(const bf16x8*)(Bgl + (size_t)((t * KSTEPS + s) * 64 + lane) * 8);
            acc0 = __builtin_amdgcn_mfma_f32_32x32x16_bf16(a0h, bh, acc0, 0, 0, 0);
            acc1 = __builtin_amdgcn_mfma_f32_32x32x16_bf16(a1h, bh, acc1, 0, 0, 0);
            acc0 = __builtin_amdgcn_mfma_f32_32x32x16_bf16(a0h, bl, acc0, 0, 0, 0);
            acc1 = __builtin_amdgcn_mfma_f32_32x32x16_bf16(a1h, bl, acc1, 0, 0, 0);
            acc0 = __builtin_amdgcn_mfma_f32_32x32x16_bf16(a0l, bh, acc0, 0, 0, 0);
            acc1 = __builtin_amdgcn_mfma_f32_32x32x16_bf16(a1l, bh, acc1, 0, 0, 0);
        }
    }
    __syncthreads();

    float* fl = (float*)AH;
    {
        int ccol = lane & 31;
        if (ccol < NCO) {
#pragma unroll
            for (int r = 0; r < 16; ++r) {
                int row = (r & 3) + 8 * (r >> 2) + 4 * (lane >> 5);
                fl[ccol * 257 + wv * 64 + row] = acc0[r];
                fl[ccol * 257 + wv * 64 + 32 + row] = acc1[r];
            }
        }
    }
    __syncthreads();

    int cg = tid >> 6, pl = tid & 63;
    int phl = pl >> 4, pw = pl & 15;
    int base_m = (2 * phl) * 32 + 2 * pw;
    unsigned rwh[9], rwl[9];
#pragma unroll
    for (int w = 0; w < 9; ++w) { rwh[w] = 0u; rwl[w] = 0u; }
#pragma unroll
    for (int e = 0; e < 2; ++e) {
        int co = cg * 2 + e;
        const float* fb = fl + co * 257 + base_m;
        float m = fmaxf(fmaxf(fb[0], fb[1]), fmaxf(fb[32], fb[33]));
        float a9[9];
        spline_acts(m, a9);
#pragma unroll
        for (int j = 0; j < 9; ++j) {
            ushort h, l2; bf16split(a9[j], h, l2);
            int c = e * 9 + j;
            if (c & 1) { rwh[c >> 1] |= (unsigned)h << 16; rwl[c >> 1] |= (unsigned)l2 << 16; }
            else       { rwh[c >> 1] |= h;                  rwl[c >> 1] |= l2; }
        }
    }
    unsigned* ubh = (unsigned*)AL;
    unsigned* ubl = (unsigned*)AL + 2560;
#pragma unroll
    for (int w = 0; w < 9; ++w) {
        ubh[pl * 40 + cg * 9 + w] = rwh[w];
        ubl[pl * 40 + cg * 9 + w] = rwl[w];
    }
    if (cg == 3) {
#pragma unroll
        for (int w = 0; w < 4; ++w) { ubh[pl * 40 + 36 + w] = 0u; ubl[pl * 40 + 36 + w] = 0u; }
    }
    __syncthreads();
    size_t base = ((size_t)b * 256 + strip * 64) * 80;
    const ushort* sbh = (const ushort*)ubh;
    const ushort* sbl = (const ushort*)ubl;
#pragma unroll
    for (int e = 0; e < 3; ++e) {
        int q = e * 256 + tid;
        if (q < 640) {
            *(uint4*)(Oh + base + q * 8) = *(const uint4*)(sbh + q * 8);
            *(uint4*)(Ol + base + q * 8) = *(const uint4*)(sbl + q * 8);
        }
    }
}

// ---------------------------------------------------------------------------
// conv34_part: split-K MFMA partial, z = dh-group (3); cin-phases looped.
// ---------------------------------------------------------------------------
template <int NPH, int NCO>
__global__ __launch_bounds__(256) void conv34_part(
    const ushort* __restrict__ Agh, const ushort* __restrict__ Agl,
    const ushort* __restrict__ Bgh, const ushort* __restrict__ Bgl,
    const ushort* __restrict__ zph, const ushort* __restrict__ zpl,
    float* __restrict__ P) {
    __shared__ ushort AH[144 * AST];
    __shared__ ushort AL[144 * AST];
    const int tid = threadIdx.x;
    const int b = blockIdx.x, half = blockIdx.y, g = blockIdx.z;
    const int r0 = half * 8;
    const int lane = tid & 63, wv = tid >> 6;

    f32x16 acc;
#pragma unroll
    for (int i = 0; i < 16; ++i) acc[i] = 0.f;

    const int m = wv * 32 + (lane & 31);
    const int sbase = (m >> 4) * 18 + (m & 15);
    const int koff = (lane >> 5) * 8;

#pragma unroll 1
    for (int p = 0; p < NPH; ++p) {
        if (p) __syncthreads();
        const ushort* ash = Agh + ((size_t)b * NPH + p) * 256 * 80;
        const ushort* asl = Agl + ((size_t)b * NPH + p) * 256 * 80;
#pragma unroll
        for (int e = 0; e < 6; ++e) {
            int idx = e * 256 + tid;
            if (idx < 1440) {
                int px = idx / 10, ch = idx - px * 10;
                int pr = px / 18, pc = px - pr * 18;
                int r = r0 - 1 + g + pr, c = pc - 1;
                bool inb = ((unsigned)r < 16u) && ((unsigned)c < 16u);
                uint4 vh, vl;
                if (inb) {
                    vh = *(const uint4*)(ash + (size_t)(r * 16 + c) * 80 + ch * 8);
                    vl = *(const uint4*)(asl + (size_t)(r * 16 + c) * 80 + ch * 8);
                } else {
                    vh = *(const uint4*)(zph + ch * 8);
                    vl = *(const uint4*)(zpl + ch * 8);
                }
                *(uint4*)(&AH[px * AST + ch * 8]) = vh;
                *(uint4*)(&AL[px * AST + ch * 8]) = vl;
            }
        }
        __syncthreads();

        const ushort* bsh = Bgh + (size_t)p * 2880 * 8;
        const ushort* bsl = Bgl + (size_t)p * 2880 * 8;
#pragma unroll
        for (int dw = 0; dw < 3; ++dw) {
            const int t = g * 3 + dw;
#pragma unroll
            for (int s = 0; s < 5; ++s) {
                bf16x8 ah = *(const bf16x8*)(&AH[(sbase + dw) * AST + s * 16 + koff]);
                bf16x8 al = *(const bf16x8*)(&AL[(sbase + dw) * AST + s * 16 + koff]);
                bf16x8 bh = *(const bf16x8*)(bsh + (size_t)((t * 5 + s) * 64 + lane) * 8);
                bf16x8 bl = *(const bf16x8*)(bsl + (size_t)((t * 5 + s) * 64 + lane) * 8);
                acc = __builtin_amdgcn_mfma_f32_32x32x16_bf16(ah, bh, acc, 0, 0, 0);
                acc = __builtin_amdgcn_mfma_f32_32x32x16_bf16(ah, bl, acc, 0, 0, 0);
                acc = __builtin_amdgcn_mfma_f32_32x32x16_bf16(al, bh, acc, 0, 0, 0);
            }
        }
    }

    int co = lane & 31;
    if (co < NCO) {
        float* pb = P + ((size_t)(g * 256 + b * 2 + half) * 128) * NCO;
#pragma unroll
        for (int r = 0; r < 16; ++r) {
            int px = wv * 32 + (r & 3) + 8 * (r >> 2) + 4 * (lane >> 5);
            pb[px * NCO + co] = acc[r];
        }
    }
}

// ---------------------------------------------------------------------------
// conv3_reduce v3: block = (b, px-quarter), all 16 couts, 64 px.
// ---------------------------------------------------------------------------
__global__ __launch_bounds__(256) void conv3_reduce(const float* __restrict__ P3,
                                                    ushort* __restrict__ A4h,
                                                    ushort* __restrict__ A4l) {
    __shared__ ushort SBH[2][64 * 80];
    __shared__ ushort SBL[2][64 * 80];
    int b = blockIdx.x, pxq = blockIdx.y;
    int t = threadIdx.x;
    int co = t & 15, pxg = t >> 4;
#pragma unroll
    for (int q = 0; q < 4; ++q) {
        int lpx64 = pxg * 4 + q;
        int px = pxq * 64 + lpx64;
        int bh = b * 2 + (px >> 7), lpx = px & 127;
        float s = 0.f;
#pragma unroll
        for (int zz = 0; zz < 3; ++zz)
            s += P3[((size_t)(zz * 256 + bh) * 128 + lpx) * 16 + co];
        float a9[9];
        spline_acts(s, a9);
        int ph = co >> 3, c8 = co & 7;
#pragma unroll
        for (int j = 0; j < 9; ++j) {
            ushort h, l2; bf16split(a9[j], h, l2);
            SBH[ph][lpx64 * 80 + c8 * 9 + j] = h;
            SBL[ph][lpx64 * 80 + c8 * 9 + j] = l2;
        }
        if (c8 == 7) {
#pragma unroll
            for (int w = 0; w < 8; ++w) {
                SBH[ph][lpx64 * 80 + 72 + w] = 0;
                SBL[ph][lpx64 * 80 + 72 + w] = 0;
            }
        }
    }
    __syncthreads();
#pragma unroll
    for (int ph = 0; ph < 2; ++ph) {
        size_t base = ((size_t)(b * 2 + ph) * 256 + pxq * 64) * 80;
#pragma unroll
        for (int e = 0; e < 3; ++e) {
            int q = e * 256 + t;
            if (q < 640) {
                *(uint4*)(A4h + base + q * 8) = *(const uint4*)(&SBH[ph][q * 8]);
                *(uint4*)(A4l + base + q * 8) = *(const uint4*)(&SBL[ph][q * 8]);
            }
        }
    }
}

// ---------------------------------------------------------------------------
// conv4_reduce_pool v2: block = (b, half); sum 3 partials + 2x2 pool.
// ---------------------------------------------------------------------------
__global__ __launch_bounds__(256) void conv4_reduce_pool(const float* __restrict__ P4,
                                                         float* __restrict__ pooled) {
    __shared__ float SM[32 * 33];
    int b = blockIdx.x, half = blockIdx.y;
    int t = threadIdx.x;
    int co = t & 31, pg = t >> 5;
    int bh = b * 2 + half;
#pragma unroll
    for (int q = 0; q < 4; ++q) {
        int pp = pg * 4 + q;
        int lr = pp >> 3, pc = pp & 7;
        int px00 = (2 * lr) * 16 + 2 * pc;
        float s00 = 0.f, s01 = 0.f, s10 = 0.f, s11 = 0.f;
#pragma unroll
        for (int zz = 0; zz < 3; ++zz) {
            const float* pb = P4 + ((size_t)(zz * 256 + bh) * 128) * 32 + co;
            s00 += pb[(size_t)px00 * 32];
            s01 += pb[(size_t)(px00 + 1) * 32];
            s10 += pb[(size_t)(px00 + 16) * 32];
            s11 += pb[(size_t)(px00 + 17) * 32];
        }
        SM[co * 33 + pp] = fmaxf(fmaxf(s00, s01), fmaxf(s10, s11));
    }
    __syncthreads();
#pragma unroll
    for (int e = 0; e < 4; ++e) {
        int idx = e * 256 + t;
        int co2 = idx >> 5, pp2 = idx & 31;
        int lr2 = pp2 >> 3, pc2 = pp2 & 7;
        pooled[(size_t)b * 2048 + co2 * 64 + (half * 4 + lr2) * 8 + pc2] = SM[co2 * 33 + pp2];
    }
}

// ---------------------------------------------------------------------------
// fc_big: 64x64 tile, 4x4/thread, K_TILE=32, split-K; float4 global staging.
// ---------------------------------------------------------------------------
template <int SPLIT>
__global__ __launch_bounds__(256) void fc_big(const float* __restrict__ A,
                                              const float* __restrict__ Wt,
                                              float* __restrict__ part,
                                              int M, int N, int K) {
    __shared__ float As[32][68];
    __shared__ float Ws[32][68];
    const int tid = threadIdx.x;
    const int tx = tid & 15, ty = tid >> 4;
    const int bm = blockIdx.y * 64, bn = blockIdx.x * 64;
    const int kc = K / SPLIT;
    const int kbeg = blockIdx.z * kc;
    float acc[4][4] = {};
    for (int k0 = kbeg; k0 < kbeg + kc; k0 += 32) {
#pragma unroll
        for (int e = 0; e < 2; ++e) {
            int q = e * 256 + tid;
            int r = q >> 3, k4 = (q & 7) * 4;
            float4 av = *(const float4*)&A[(size_t)(bm + r) * K + k0 + k4];
            float4 wv = *(const float4*)&Wt[(size_t)(bn + r) * K + k0 + k4];
            As[k4 + 0][r] = av.x; As[k4 + 1][r] = av.y;
            As[k4 + 2][r] = av.z; As[k4 + 3][r] = av.w;
            Ws[k4 + 0][r] = wv.x; Ws[k4 + 1][r] = wv.y;
            Ws[k4 + 2][r] = wv.z; Ws[k4 + 3][r] = wv.w;
        }
        __syncthreads();
#pragma unroll
        for (int kk = 0; kk < 32; ++kk) {
            float4 av = *(const float4*)(&As[kk][ty * 4]);
            float4 wv = *(const float4*)(&Ws[kk][tx * 4]);
            acc[0][0] = fmaf(av.x, wv.x, acc[0][0]);
            acc[0][1] = fmaf(av.x, wv.y, acc[0][1]);
            acc[0][2] = fmaf(av.x, wv.z, acc[0][2]);
            acc[0][3] = fmaf(av.x, wv.w, acc[0][3]);
            acc[1][0] = fmaf(av.y, wv.x, acc[1][0]);
            acc[1][1] = fmaf(av.y, wv.y, acc[1][1]);
            acc[1][2] = fmaf(av.y, wv.z, acc[1][2]);
            acc[1][3] = fmaf(av.y, wv.w, acc[1][3]);
            acc[2][0] = fmaf(av.z, wv.x, acc[2][0]);
            acc[2][1] = fmaf(av.z, wv.y, acc[2][1]);
            acc[2][2] = fmaf(av.z, wv.z, acc[2][2]);
            acc[2][3] = fmaf(av.z, wv.w, acc[2][3]);
            acc[3][0] = fmaf(av.w, wv.x, acc[3][0]);
            acc[3][1] = fmaf(av.w, wv.y, acc[3][1]);
            acc[3][2] = fmaf(av.w, wv.z, acc[3][2]);
            acc[3][3] = fmaf(av.w, wv.w, acc[3][3]);
        }
        __syncthreads();
    }
    float* p = part + (size_t)blockIdx.z * M * N;
#pragma unroll
    for (int i = 0; i < 4; ++i) {
        float4 v = make_float4(acc[i][0], acc[i][1], acc[i][2], acc[i][3]);
        *(float4*)&p[(size_t)(bm + ty * 4 + i) * N + (bn + tx * 4)] = v;
    }
}

template <int SPLIT>
__global__ void fc_reduce(const float* __restrict__ part, const float* __restrict__ bias,
                          float* __restrict__ C, int MN, int N, int relu) {
    int i = blockIdx.x * 256 + threadIdx.x;
    if (i >= MN) return;
    float s = bias[i % N];
#pragma unroll
    for (int z = 0; z < SPLIT; ++z) s += part[(size_t)z * MN + i];
    C[i] = relu ? fmaxf(s, 0.f) : s;
}

// ---------------------------------------------------------------------------
// fc3_fused: inline fc2 reduce (relu(bias2 + sum_z part2[z])) + final dot.
// One wave per (m,n); identical arithmetic order to reduce-then-dot.
// ---------------------------------------------------------------------------
__global__ __launch_bounds__(256) void fc3_fused(const float* __restrict__ part2,
                                                 const float* __restrict__ bias2,
                                                 const float* __restrict__ Wt,
                                                 const float* __restrict__ bias,
                                                 float* __restrict__ C) {
    int gid = blockIdx.x * 256 + threadIdx.x;
    int wid = gid >> 6;
    int lane = gid & 63;
    int m = wid / 10, n = wid - m * 10;
    const float4* w = (const float4*)(Wt + (size_t)n * 1024);
    const float4* b2 = (const float4*)bias2;
    float s = 0.f;
#pragma unroll
    for (int it = 0; it < 4; ++it) {
        int k4 = it * 64 + lane;              // float4 index into the 1024-row
        float4 av = b2[k4 & 255];             // bias2[k], k = k4*4.. (row-major)
        // accumulate 8 split-K slices (each slice = (128,1024) fp32)
#pragma unroll
        for (int z = 0; z < 8; ++z) {
            float4 pv = *(const float4*)&part2[(size_t)z * 131072 + (size_t)m * 1024 + k4 * 4];
            av.x += pv.x; av.y += pv.y; av.z += pv.z; av.w += pv.w;
        }
        av.x = fmaxf(av.x, 0.f); av.y = fmaxf(av.y, 0.f);
        av.z = fmaxf(av.z, 0.f); av.w = fmaxf(av.w, 0.f);
        float4 wv = w[k4];
        s += av.x * wv.x + av.y * wv.y + av.z * wv.z + av.w * wv.w;
    }
#pragma unroll
    for (int off = 32; off; off >>= 1) s += __shfl_xor(s, off);
    if (lane == 0) C[wid] = s + bias[n];
}

// ---------------------------------------------------------------------------
extern "C" void kernel_launch(void* const* d_in, const int* in_sizes, int n_in,
                              void* d_out, int out_size, void* d_ws, size_t ws_size,
                              hipStream_t stream) {
    const float* x   = (const float*)d_in[0];
    const float* bw1 = (const float*)d_in[1];
    const float* sw1 = (const float*)d_in[2];
    const float* sc1 = (const float*)d_in[3];
    const float* bw2 = (const float*)d_in[4];
    const float* sw2 = (const float*)d_in[5];
    const float* sc2 = (const float*)d_in[6];
    const float* bw3 = (const float*)d_in[7];
    const float* sw3 = (const float*)d_in[8];
    const float* sc3 = (const float*)d_in[9];
    const float* bw4 = (const float*)d_in[10];
    const float* sw4 = (const float*)d_in[11];
    const float* sc4 = (const float*)d_in[12];
    const float* w1  = (const float*)d_in[13];
    const float* b1  = (const float*)d_in[14];
    const float* w2  = (const float*)d_in[15];
    const float* b2  = (const float*)d_in[16];
    const float* w3  = (const float*)d_in[17];
    const float* b3  = (const float*)d_in[18];

    float*  wsf = (float*)d_ws;
    ushort* wsu = (ushort*)d_ws;
    ushort* k1h = wsu + 110848;
    ushort* k1l = wsu + 120064;
    ushort* k2h = wsu + 129280;
    ushort* k2l = wsu + 143104;
    ushort* k3h = wsu + 156928;
    ushort* k3l = wsu + 179968;
    ushort* k4h = wsu + 203008;
    ushort* k4l = wsu + 249088;
    ushort* zph = wsu + 295168;
    ushort* zpl = wsu + 295248;
    ushort* A2h = wsu + 7864320;    // (B,1024,36)
    ushort* A2l = wsu + 12582912;
    ushort* A3h = wsu + 524288;     // (B,256,80)
    ushort* A3l = wsu + 3145728;
    ushort* A4h = wsu + 5767168;    // (B,2,256,80)
    ushort* A4l = wsu + 11010048;
    float* P3   = wsf + 9437184;    // 3x256x128x16 fp32
    float* P4   = wsf + 11534336;   // 3x256x128x32 fp32
    float* pooled = wsf + 262144;
    float* part1  = wsf + 524288;
    float* fc1o   = wsf + 2621440;
    float* part2  = wsf + 2883584;  // 8x(128,1024)

    prep_kernel<<<46, 256, 0, stream>>>(bw1, sw1, sc1, bw2, sw2, sc2,
                                        bw3, sw3, sc3, bw4, sw4, sc4,
                                        k1h, k1l, k2h, k2l, k3h, k3l, k4h, k4l,
                                        zph, zpl);

    conv1_fused<<<1024, 256, 0, stream>>>(x, k1h, k1l, A2h, A2l);
    conv2_strip<36, 9, 12, 56, 3, 8><<<512, 256, 0, stream>>>(A2h, A2l, k2h, k2l,
                                                              zph, zpl, A3h, A3l);
    conv34_part<1, 16><<<dim3(128, 2, 3), 256, 0, stream>>>(A3h, A3l, k3h, k3l,
                                                            zph, zpl, P3);
    conv3_reduce<<<dim3(128, 4), 256, 0, stream>>>(P3, A4h, A4l);
    conv34_part<2, 32><<<dim3(128, 2, 3), 256, 0, stream>>>(A4h, A4l, k4h, k4l,
                                                            zph, zpl, P4);
    conv4_reduce_pool<<<dim3(128, 2), 256, 0, stream>>>(P4, pooled);

    fc_big<8><<<dim3(32, 2, 8), 256, 0, stream>>>(pooled, w1, part1, 128, 2048, 2048);
    fc_reduce<8><<<1024, 256, 0, stream>>>(part1, b1, fc1o, 262144, 2048, 1);
    fc_big<8><<<dim3(16, 2, 8), 256, 0, stream>>>(fc1o, w2, part2, 128, 1024, 2048);
    // fc2 reduce + fc3 fused (one fewer dispatch)
    fc3_fused<<<320, 256, 0, stream>>>(part2, b2, w3, b3, (float*)d_out);
}